// Round 1
// baseline (614.578 us; speedup 1.0000x reference)
//
#include <hip/hip_runtime.h>
#include <hip/hip_bf16.h>
#include <math.h>

#define NODES 30000
#define WAVE 64

static __device__ __forceinline__ float lrelu(float x) {
    return (x > 0.f) ? x : 0.2f * x;
}

// ---------------------------------------------------------------------------
// GEMM: out[N,M] = X[N,K] @ W[M,K]^T  (+bias, optional relu)
// 64x64 tile, 256 threads, 4x4 micro-tile, K staged in 16-chunks in LDS.
// Gated device-side on (*flag != 0) == wantFlag.
// ---------------------------------------------------------------------------
__global__ __launch_bounds__(256) void gemm_xwt(
    const float* __restrict__ X, const float* __restrict__ W,
    const float* __restrict__ bias, float* __restrict__ out,
    int Nrows, int M, int K, int relu,
    const int* __restrict__ flag, int wantFlag)
{
    if (((*flag != 0) ? 1 : 0) != wantFlag) return;

    __shared__ float As[16][68];  // [k][row], padded
    __shared__ float Bs[16][68];  // [k][col], padded

    const int t  = threadIdx.x;
    const int tx = t & 15;
    const int ty = t >> 4;
    const int rowBase = blockIdx.y * 64;
    const int colBase = blockIdx.x * 64;

    float acc[4][4];
#pragma unroll
    for (int i = 0; i < 4; i++)
#pragma unroll
        for (int j = 0; j < 4; j++) acc[i][j] = 0.f;

    const int r_ld = t >> 2;        // 0..63
    const int k_ld = (t & 3) * 4;   // 0,4,8,12

    for (int kt = 0; kt < K; kt += 16) {
        // stage A tile (transposed: As[k][row])
        float4 av = make_float4(0.f, 0.f, 0.f, 0.f);
        int grow = rowBase + r_ld;
        if (grow < Nrows)
            av = *reinterpret_cast<const float4*>(&X[(size_t)grow * K + kt + k_ld]);
        As[k_ld + 0][r_ld] = av.x;
        As[k_ld + 1][r_ld] = av.y;
        As[k_ld + 2][r_ld] = av.z;
        As[k_ld + 3][r_ld] = av.w;
        // stage B tile (Bs[k][m] = W[m][k])
        float4 bv = make_float4(0.f, 0.f, 0.f, 0.f);
        int gm = colBase + r_ld;
        if (gm < M)
            bv = *reinterpret_cast<const float4*>(&W[(size_t)gm * K + kt + k_ld]);
        Bs[k_ld + 0][r_ld] = bv.x;
        Bs[k_ld + 1][r_ld] = bv.y;
        Bs[k_ld + 2][r_ld] = bv.z;
        Bs[k_ld + 3][r_ld] = bv.w;
        __syncthreads();

#pragma unroll
        for (int kk = 0; kk < 16; ++kk) {
            const float4 a = *reinterpret_cast<const float4*>(&As[kk][ty * 4]);
            const float4 b = *reinterpret_cast<const float4*>(&Bs[kk][tx * 4]);
            acc[0][0] += a.x * b.x; acc[0][1] += a.x * b.y; acc[0][2] += a.x * b.z; acc[0][3] += a.x * b.w;
            acc[1][0] += a.y * b.x; acc[1][1] += a.y * b.y; acc[1][2] += a.y * b.z; acc[1][3] += a.y * b.w;
            acc[2][0] += a.z * b.x; acc[2][1] += a.z * b.y; acc[2][2] += a.z * b.z; acc[2][3] += a.z * b.w;
            acc[3][0] += a.w * b.x; acc[3][1] += a.w * b.y; acc[3][2] += a.w * b.z; acc[3][3] += a.w * b.w;
        }
        __syncthreads();
    }

#pragma unroll
    for (int i = 0; i < 4; i++) {
        int row = rowBase + ty * 4 + i;
        if (row >= Nrows) continue;
        int col0 = colBase + tx * 4;
        if (col0 >= M) continue;
        float4 v = make_float4(acc[i][0], acc[i][1], acc[i][2], acc[i][3]);
        if (bias) {
            v.x += bias[col0 + 0]; v.y += bias[col0 + 1];
            v.z += bias[col0 + 2]; v.w += bias[col0 + 3];
        }
        if (relu) {
            v.x = fmaxf(v.x, 0.f); v.y = fmaxf(v.y, 0.f);
            v.z = fmaxf(v.z, 0.f); v.w = fmaxf(v.w, 0.f);
        }
        *reinterpret_cast<float4*>(&out[(size_t)row * M + col0]) = v;
    }
}

// ---------------------------------------------------------------------------
// Attention dots: a_s[n,h] = sum_f h[n, h*F+f] * att_src[h*F+f]  (same for a_d)
// One wave per node.
// ---------------------------------------------------------------------------
__global__ __launch_bounds__(256) void att_dots(
    const float* __restrict__ h, const float* __restrict__ att_s,
    const float* __restrict__ att_d, float* __restrict__ as_out,
    float* __restrict__ ad_out, int HF, int F,
    const int* __restrict__ flag)
{
    if (*flag == 0) return;
    int node = blockIdx.x * (blockDim.x >> 6) + (threadIdx.x >> 6);
    int lane = threadIdx.x & 63;
    if (node >= NODES) return;

    float ps[2] = {0.f, 0.f}, pd[2] = {0.f, 0.f};
    const float* row = h + (size_t)node * HF;
    for (int idx = lane; idx < HF; idx += WAVE) {
        int hd = idx / F;
        float v = row[idx];
        ps[hd] += v * att_s[idx];
        pd[hd] += v * att_d[idx];
    }
#pragma unroll
    for (int off = 32; off; off >>= 1) {
        ps[0] += __shfl_xor(ps[0], off);
        ps[1] += __shfl_xor(ps[1], off);
        pd[0] += __shfl_xor(pd[0], off);
        pd[1] += __shfl_xor(pd[1], off);
    }
    int Hh = HF / F;
    if (lane == 0) {
        for (int hd = 0; hd < Hh; hd++) {
            as_out[node * Hh + hd] = ps[hd];
            ad_out[node * Hh + hd] = pd[hd];
        }
    }
}

// ---------------------------------------------------------------------------
// Fused GAT aggregation: per dst node (one wave): segment max -> denom ->
// weighted accumulate of h[src] rows -> +bias (+relu). No atomics.
// ---------------------------------------------------------------------------
template <int HF, int F, int HH, int RELU>
__global__ __launch_bounds__(256) void gat_aggr(
    const float* __restrict__ hsrc, const float* __restrict__ as_,
    const float* __restrict__ ad_, const int* __restrict__ rowptr,
    const int* __restrict__ csr_src, const float* __restrict__ bias,
    float* __restrict__ out, const int* __restrict__ flag)
{
    if (*flag == 0) return;
    int node = blockIdx.x * (blockDim.x >> 6) + (threadIdx.x >> 6);
    int lane = threadIdx.x & 63;
    if (node >= NODES) return;

    const int beg = rowptr[node], end = rowptr[node + 1];

    float adv[HH], mx[HH], den[HH];
#pragma unroll
    for (int h = 0; h < HH; h++) {
        adv[h] = ad_[node * HH + h];
        mx[h]  = -INFINITY;
        den[h] = 0.f;
    }
    // pass 1: segment max
    for (int i = beg + lane; i < end; i += WAVE) {
        int s = csr_src[i];
#pragma unroll
        for (int h = 0; h < HH; h++) {
            float e = lrelu(as_[s * HH + h] + adv[h]);
            mx[h] = fmaxf(mx[h], e);
        }
    }
#pragma unroll
    for (int h = 0; h < HH; h++)
#pragma unroll
        for (int off = 32; off; off >>= 1)
            mx[h] = fmaxf(mx[h], __shfl_xor(mx[h], off));
    // pass 2: denominator
    for (int i = beg + lane; i < end; i += WAVE) {
        int s = csr_src[i];
#pragma unroll
        for (int h = 0; h < HH; h++) {
            float e = lrelu(as_[s * HH + h] + adv[h]);
            den[h] += __expf(e - mx[h]);
        }
    }
#pragma unroll
    for (int h = 0; h < HH; h++)
#pragma unroll
        for (int off = 32; off; off >>= 1)
            den[h] += __shfl_xor(den[h], off);

    // pass 3: weighted accumulate (lanes own columns)
    constexpr int CPL = (HF + WAVE - 1) / WAVE;
    float acc[CPL];
#pragma unroll
    for (int c = 0; c < CPL; c++) acc[c] = 0.f;

    for (int i = beg; i < end; i++) {
        int s = csr_src[i];
        float w[HH];
#pragma unroll
        for (int h = 0; h < HH; h++) {
            float e = lrelu(as_[s * HH + h] + adv[h]);
            w[h] = __expf(e - mx[h]);
        }
        const float* row = hsrc + (size_t)s * HF;
#pragma unroll
        for (int c = 0; c < CPL; c++) {
            int col = lane + c * WAVE;
            if ((HF % WAVE == 0) || col < HF)
                acc[c] += row[col] * w[(F == HF) ? 0 : (col / F)];
        }
    }
#pragma unroll
    for (int c = 0; c < CPL; c++) {
        int col = lane + c * WAVE;
        if ((HF % WAVE == 0) || col < HF) {
            int h = (F == HF) ? 0 : (col / F);
            float v = acc[c] / den[h] + bias[col];
            if (RELU) v = fmaxf(v, 0.f);
            out[(size_t)node * HF + col] = v;
        }
    }
}

// ---------------------------------------------------------------------------
// CSR build kernels (gated on flag != 0)
// ---------------------------------------------------------------------------
__global__ void zero_int(int* __restrict__ p, int n, const int* __restrict__ flag)
{
    if (*flag == 0) return;
    for (int i = blockIdx.x * blockDim.x + threadIdx.x; i < n; i += gridDim.x * blockDim.x)
        p[i] = 0;
}

__global__ void count_deg(const int* __restrict__ ei, int* __restrict__ deg,
                          int E_, int Nn, const int* __restrict__ flag)
{
    if (*flag == 0) return;
    int e = blockIdx.x * blockDim.x + threadIdx.x;
    int tot = E_ + Nn;
    if (e >= tot) return;
    int dst = (e < E_) ? ei[E_ + e] : (e - E_);
    atomicAdd(&deg[dst], 1);
}

__global__ __launch_bounds__(1024) void scan_deg(
    const int* __restrict__ deg, int* __restrict__ rowptr, int n,
    const int* __restrict__ flag)
{
    if (*flag == 0) return;
    __shared__ int temp[1024];
    __shared__ int carry;
    const int t = threadIdx.x;
    if (t == 0) { carry = 0; rowptr[0] = 0; }
    __syncthreads();
    for (int base = 0; base < n; base += 1024) {
        int i = base + t;
        int v = (i < n) ? deg[i] : 0;
        temp[t] = v;
        __syncthreads();
        for (int off = 1; off < 1024; off <<= 1) {
            int x = (t >= off) ? temp[t - off] : 0;
            __syncthreads();
            temp[t] += x;
            __syncthreads();
        }
        if (i < n) rowptr[i + 1] = carry + temp[t];
        __syncthreads();
        if (t == 0) carry += temp[1023];
        __syncthreads();
    }
}

__global__ void copy_int(const int* __restrict__ a, int* __restrict__ b, int n,
                         const int* __restrict__ flag)
{
    if (*flag == 0) return;
    for (int i = blockIdx.x * blockDim.x + threadIdx.x; i < n; i += gridDim.x * blockDim.x)
        b[i] = a[i];
}

__global__ void scatter_edges(const int* __restrict__ ei, int* __restrict__ cursor,
                              int* __restrict__ csr_src, int E_, int Nn,
                              const int* __restrict__ flag)
{
    if (*flag == 0) return;
    int e = blockIdx.x * blockDim.x + threadIdx.x;
    int tot = E_ + Nn;
    if (e >= tot) return;
    int src, dst;
    if (e < E_) { src = ei[e]; dst = ei[E_ + e]; }
    else        { src = e - E_; dst = src; }
    int pos = atomicAdd(&cursor[dst], 1);
    csr_src[pos] = src;
}

// ---------------------------------------------------------------------------
extern "C" void kernel_launch(void* const* d_in, const int* in_sizes, int n_in,
                              void* d_out, int out_size, void* d_ws, size_t ws_size,
                              hipStream_t stream)
{
    const float* x    = (const float*)d_in[0];
    const int*   ei   = (const int*)d_in[1];
    const int*   flag = (const int*)d_in[2];
    const float* W1 = (const float*)d_in[3];
    const float* as1 = (const float*)d_in[4];
    const float* ad1 = (const float*)d_in[5];
    const float* b1 = (const float*)d_in[6];
    const float* W2 = (const float*)d_in[7];
    const float* as2 = (const float*)d_in[8];
    const float* ad2 = (const float*)d_in[9];
    const float* b2 = (const float*)d_in[10];
    const float* W3 = (const float*)d_in[11];
    const float* as3 = (const float*)d_in[12];
    const float* ad3 = (const float*)d_in[13];
    const float* b3 = (const float*)d_in[14];
    const float* W4 = (const float*)d_in[15];
    const float* as4 = (const float*)d_in[16];
    const float* ad4 = (const float*)d_in[17];
    const float* b4 = (const float*)d_in[18];
    const float* el1w = (const float*)d_in[19];
    const float* el1b = (const float*)d_in[20];
    const float* el2w = (const float*)d_in[21];
    const float* el2b = (const float*)d_in[22];
    const float* dl1w = (const float*)d_in[23];
    const float* dl1b = (const float*)d_in[24];
    const float* dl2w = (const float*)d_in[25];
    const float* dl2b = (const float*)d_in[26];

    const int E_   = in_sizes[1] / 2;
    const int Etot = E_ + NODES;

    // workspace carve (float buffers then int buffers), 256B aligned
    char* base = (char*)d_ws;
    size_t off = 0;
    auto carve = [&](size_t bytes) -> void* {
        void* p = base + off;
        off = (off + bytes + 255) & ~(size_t)255;
        return p;
    };
    float* T0  = (float*)carve((size_t)NODES * 256 * 4);  // gemm output (pre-aggregation)
    float* A   = (float*)carve((size_t)NODES * 256 * 4);  // aggregated layer1/3 output
    float* T1  = (float*)carve((size_t)NODES * 64 * 4);   // gemm output layers 2/4
    float* Bz  = (float*)carve((size_t)NODES * 32 * 4);   // z (layer2 output)
    float* asb = (float*)carve((size_t)NODES * 2 * 4);
    float* adb = (float*)carve((size_t)NODES * 2 * 4);
    int* deg    = (int*)carve((size_t)NODES * 4);
    int* rowptr = (int*)carve((size_t)(NODES + 1) * 4);
    int* cursor = (int*)carve((size_t)NODES * 4);
    int* csr    = (int*)carve((size_t)Etot * 4);
    (void)ws_size; (void)n_in; (void)out_size;

    float* outp = (float*)d_out;

    const int nodeBlocks = (NODES + 3) / 4;  // 4 waves (nodes) per 256-thread block

    // ---- CSR build (GAT path only) ----
    zero_int<<<(NODES + 255) / 256, 256, 0, stream>>>(deg, NODES, flag);
    count_deg<<<(Etot + 255) / 256, 256, 0, stream>>>(ei, deg, E_, NODES, flag);
    scan_deg<<<1, 1024, 0, stream>>>(deg, rowptr, NODES, flag);
    copy_int<<<(NODES + 255) / 256, 256, 0, stream>>>(rowptr, cursor, NODES, flag);
    scatter_edges<<<(Etot + 255) / 256, 256, 0, stream>>>(ei, cursor, csr, E_, NODES, flag);

    dim3 blk(256);
    const int rowTiles = (NODES + 63) / 64;

    // ---- Layer 1: GAT(in=64, out=128, heads=2) + ReLU ----
    gemm_xwt<<<dim3(4, rowTiles), blk, 0, stream>>>(x, W1, nullptr, T0, NODES, 256, 64, 0, flag, 1);
    att_dots<<<nodeBlocks, blk, 0, stream>>>(T0, as1, ad1, asb, adb, 256, 128, flag);
    gat_aggr<256, 128, 2, 1><<<nodeBlocks, blk, 0, stream>>>(T0, asb, adb, rowptr, csr, b1, A, flag);

    // ---- Layer 2: GAT(in=256, out=32, heads=1) ----
    gemm_xwt<<<dim3(1, rowTiles), blk, 0, stream>>>(A, W2, nullptr, T1, NODES, 32, 256, 0, flag, 1);
    att_dots<<<nodeBlocks, blk, 0, stream>>>(T1, as2, ad2, asb, adb, 32, 32, flag);
    gat_aggr<32, 32, 1, 0><<<nodeBlocks, blk, 0, stream>>>(T1, asb, adb, rowptr, csr, b2, Bz, flag);

    // ---- Layer 3: GAT(in=32, out=128, heads=2) + ReLU ----
    gemm_xwt<<<dim3(4, rowTiles), blk, 0, stream>>>(Bz, W3, nullptr, T0, NODES, 256, 32, 0, flag, 1);
    att_dots<<<nodeBlocks, blk, 0, stream>>>(T0, as3, ad3, asb, adb, 256, 128, flag);
    gat_aggr<256, 128, 2, 1><<<nodeBlocks, blk, 0, stream>>>(T0, asb, adb, rowptr, csr, b3, A, flag);

    // ---- Layer 4: GAT(in=256, out=64, heads=1) ----
    gemm_xwt<<<dim3(1, rowTiles), blk, 0, stream>>>(A, W4, nullptr, T1, NODES, 64, 256, 0, flag, 1);
    att_dots<<<nodeBlocks, blk, 0, stream>>>(T1, as4, ad4, asb, adb, 64, 64, flag);
    gat_aggr<64, 64, 1, 0><<<nodeBlocks, blk, 0, stream>>>(T1, asb, adb, rowptr, csr, b4, outp, flag);

    // ---- Dense path (use_neighbors == 0) ----
    gemm_xwt<<<dim3(2, rowTiles), blk, 0, stream>>>(x,  el1w, el1b, T0,  NODES, 128, 64, 1, flag, 0);
    gemm_xwt<<<dim3(1, rowTiles), blk, 0, stream>>>(T0, el2w, el2b, Bz,  NODES, 32, 128, 0, flag, 0);
    gemm_xwt<<<dim3(2, rowTiles), blk, 0, stream>>>(Bz, dl1w, dl1b, A,   NODES, 128, 32, 1, flag, 0);
    gemm_xwt<<<dim3(1, rowTiles), blk, 0, stream>>>(A,  dl2w, dl2b, outp, NODES, 64, 128, 0, flag, 0);
}

// Round 2
// 593.350 us; speedup vs baseline: 1.0358x; 1.0358x over previous
//
#include <hip/hip_runtime.h>
#include <hip/hip_bf16.h>
#include <math.h>

#define NODES 30000
#define WAVE 64

static __device__ __forceinline__ float lrelu(float x) {
    return (x > 0.f) ? x : 0.2f * x;
}

// ---------------------------------------------------------------------------
// GEMM: out[n, z*M + m] = X[n, z*K + k] @ W[z*M + m, k]^T  (+bias, opt relu)
// lda/ldc row strides; blockIdx.z = head (weight block-diagonal).
// 64x64 tile, 256 threads, 4x4 micro-tile, K staged 16 at a time in LDS.
// ---------------------------------------------------------------------------
__global__ __launch_bounds__(256) void gemm_xwt(
    const float* __restrict__ X, int lda, const float* __restrict__ W,
    const float* __restrict__ bias, float* __restrict__ out, int ldc,
    int Nrows, int M, int K, int relu,
    const int* __restrict__ flag, int wantFlag)
{
    if (((*flag != 0) ? 1 : 0) != wantFlag) return;

    const int z = blockIdx.z;
    X += (size_t)z * K;            // head's input columns
    W += (size_t)z * M * K;        // head's weight block
    if (bias) bias += (size_t)z * M;
    out += (size_t)z * M;          // head's output columns

    __shared__ float As[16][68];   // [k][row]
    __shared__ float Bs[16][68];   // [k][col]

    const int t  = threadIdx.x;
    const int tx = t & 15;
    const int ty = t >> 4;
    const int rowBase = blockIdx.y * 64;
    const int colBase = blockIdx.x * 64;

    float acc[4][4];
#pragma unroll
    for (int i = 0; i < 4; i++)
#pragma unroll
        for (int j = 0; j < 4; j++) acc[i][j] = 0.f;

    const int r_ld = t >> 2;        // 0..63
    const int k_ld = (t & 3) * 4;   // 0,4,8,12

    for (int kt = 0; kt < K; kt += 16) {
        float4 av = make_float4(0.f, 0.f, 0.f, 0.f);
        int grow = rowBase + r_ld;
        if (grow < Nrows)
            av = *reinterpret_cast<const float4*>(&X[(size_t)grow * lda + kt + k_ld]);
        As[k_ld + 0][r_ld] = av.x;
        As[k_ld + 1][r_ld] = av.y;
        As[k_ld + 2][r_ld] = av.z;
        As[k_ld + 3][r_ld] = av.w;
        float4 bv = make_float4(0.f, 0.f, 0.f, 0.f);
        int gm = colBase + r_ld;
        if (gm < M)
            bv = *reinterpret_cast<const float4*>(&W[(size_t)gm * K + kt + k_ld]);
        Bs[k_ld + 0][r_ld] = bv.x;
        Bs[k_ld + 1][r_ld] = bv.y;
        Bs[k_ld + 2][r_ld] = bv.z;
        Bs[k_ld + 3][r_ld] = bv.w;
        __syncthreads();

#pragma unroll
        for (int kk = 0; kk < 16; ++kk) {
            const float4 a = *reinterpret_cast<const float4*>(&As[kk][ty * 4]);
            const float4 b = *reinterpret_cast<const float4*>(&Bs[kk][tx * 4]);
            acc[0][0] += a.x * b.x; acc[0][1] += a.x * b.y; acc[0][2] += a.x * b.z; acc[0][3] += a.x * b.w;
            acc[1][0] += a.y * b.x; acc[1][1] += a.y * b.y; acc[1][2] += a.y * b.z; acc[1][3] += a.y * b.w;
            acc[2][0] += a.z * b.x; acc[2][1] += a.z * b.y; acc[2][2] += a.z * b.z; acc[2][3] += a.z * b.w;
            acc[3][0] += a.w * b.x; acc[3][1] += a.w * b.y; acc[3][2] += a.w * b.z; acc[3][3] += a.w * b.w;
        }
        __syncthreads();
    }

#pragma unroll
    for (int i = 0; i < 4; i++) {
        int row = rowBase + ty * 4 + i;
        if (row >= Nrows) continue;
        int col0 = colBase + tx * 4;
        if (col0 >= M) continue;
        float4 v = make_float4(acc[i][0], acc[i][1], acc[i][2], acc[i][3]);
        if (bias) {
            v.x += bias[col0 + 0]; v.y += bias[col0 + 1];
            v.z += bias[col0 + 2]; v.w += bias[col0 + 3];
        }
        if (relu) {
            v.x = fmaxf(v.x, 0.f); v.y = fmaxf(v.y, 0.f);
            v.z = fmaxf(v.z, 0.f); v.w = fmaxf(v.w, 0.f);
        }
        *reinterpret_cast<float4*>(&out[(size_t)row * ldc + col0]) = v;
    }
}

// ---------------------------------------------------------------------------
// Fold attention vectors into input space: u[h,k] = sum_f att[h,f] * W[h*F+f, k]
// One block of 256 threads handles both u_s and u_d.
// ---------------------------------------------------------------------------
__global__ void fold_att(const float* __restrict__ W, const float* __restrict__ as_,
                         const float* __restrict__ ad_, float* __restrict__ us,
                         float* __restrict__ ud, int Hh, int F, int K,
                         const int* __restrict__ flag)
{
    if (*flag == 0) return;
    int t = blockIdx.x * blockDim.x + threadIdx.x;
    int tot = 2 * Hh * K;
    if (t >= tot) return;
    int sel = t / (Hh * K);
    int r = t % (Hh * K);
    int h = r / K, k = r % K;
    const float* att = sel ? ad_ : as_;
    float s = 0.f;
    for (int f = 0; f < F; f++)
        s += att[h * F + f] * W[(size_t)(h * F + f) * K + k];
    (sel ? ud : us)[r] = s;
}

// ---------------------------------------------------------------------------
// a_s[n,h] = x[n,:] . u_s[h,:]  (and a_d). One wave per node.
// ---------------------------------------------------------------------------
template <int K, int HH>
__global__ __launch_bounds__(256) void att_from_x(
    const float* __restrict__ xin, const float* __restrict__ us,
    const float* __restrict__ ud, float* __restrict__ as_out,
    float* __restrict__ ad_out, const int* __restrict__ flag)
{
    if (*flag == 0) return;
    int node = blockIdx.x * (blockDim.x >> 6) + (threadIdx.x >> 6);
    int lane = threadIdx.x & 63;
    if (node >= NODES) return;

    float v = (lane < K) ? xin[(size_t)node * K + lane] : 0.f;
    float ps[HH], pd[HH];
#pragma unroll
    for (int h = 0; h < HH; h++) {
        ps[h] = (lane < K) ? v * us[h * K + lane] : 0.f;
        pd[h] = (lane < K) ? v * ud[h * K + lane] : 0.f;
    }
#pragma unroll
    for (int off = 32; off; off >>= 1) {
#pragma unroll
        for (int h = 0; h < HH; h++) {
            ps[h] += __shfl_xor(ps[h], off);
            pd[h] += __shfl_xor(pd[h], off);
        }
    }
    if (lane == 0) {
#pragma unroll
        for (int h = 0; h < HH; h++) {
            as_out[node * HH + h] = ps[h];
            ad_out[node * HH + h] = pd[h];
        }
    }
}

// ---------------------------------------------------------------------------
// Aggregate RAW INPUT rows with per-head softmax weights:
// agg[n, h*K + k] = sum_src alpha[src,h] * xin[src, k]
// One wave per dst node. K=64: 1 edge/iter; K=32: 2 edges/iter.
// ---------------------------------------------------------------------------
template <int K, int HH>
__global__ __launch_bounds__(256) void gat_aggr_x(
    const float* __restrict__ xin, const float* __restrict__ as_,
    const float* __restrict__ ad_, const int* __restrict__ rowptr,
    const int* __restrict__ csr_src, float* __restrict__ agg,
    const int* __restrict__ flag)
{
    if (*flag == 0) return;
    int node = blockIdx.x * (blockDim.x >> 6) + (threadIdx.x >> 6);
    int lane = threadIdx.x & 63;
    if (node >= NODES) return;

    const int beg = rowptr[node], end = rowptr[node + 1];

    float adv[HH], mx[HH], den[HH];
#pragma unroll
    for (int h = 0; h < HH; h++) {
        adv[h] = ad_[node * HH + h];
        mx[h]  = -INFINITY;
        den[h] = 0.f;
    }
    for (int i = beg + lane; i < end; i += WAVE) {
        int s = csr_src[i];
#pragma unroll
        for (int h = 0; h < HH; h++)
            mx[h] = fmaxf(mx[h], lrelu(as_[s * HH + h] + adv[h]));
    }
#pragma unroll
    for (int h = 0; h < HH; h++)
#pragma unroll
        for (int off = 32; off; off >>= 1)
            mx[h] = fmaxf(mx[h], __shfl_xor(mx[h], off));
    for (int i = beg + lane; i < end; i += WAVE) {
        int s = csr_src[i];
#pragma unroll
        for (int h = 0; h < HH; h++)
            den[h] += __expf(lrelu(as_[s * HH + h] + adv[h]) - mx[h]);
    }
#pragma unroll
    for (int h = 0; h < HH; h++)
#pragma unroll
        for (int off = 32; off; off >>= 1)
            den[h] += __shfl_xor(den[h], off);

    constexpr int EPI = WAVE / K;                 // 1 or 2
    const int e_sub = (EPI > 1) ? (lane / K) : 0;
    const int col   = (EPI > 1) ? (lane % K) : lane;

    float acc[HH];
#pragma unroll
    for (int h = 0; h < HH; h++) acc[h] = 0.f;

    for (int i = beg + e_sub; i < end; i += EPI) {
        int s = csr_src[i];
        float w[HH];
#pragma unroll
        for (int h = 0; h < HH; h++)
            w[h] = __expf(lrelu(as_[s * HH + h] + adv[h]) - mx[h]);
        float v = xin[(size_t)s * K + col];
#pragma unroll
        for (int h = 0; h < HH; h++) acc[h] += v * w[h];
    }
    if (EPI > 1) {
#pragma unroll
        for (int h = 0; h < HH; h++) acc[h] += __shfl_xor(acc[h], K);
    }
    if (lane < K) {
#pragma unroll
        for (int h = 0; h < HH; h++)
            agg[(size_t)node * (HH * K) + h * K + col] = acc[h] / den[h];
    }
}

// ---------------------------------------------------------------------------
// Attention dots on projected features (layers 2/4): one wave per node.
// ---------------------------------------------------------------------------
__global__ __launch_bounds__(256) void att_dots(
    const float* __restrict__ h, const float* __restrict__ att_s,
    const float* __restrict__ att_d, float* __restrict__ as_out,
    float* __restrict__ ad_out, int HF, int F,
    const int* __restrict__ flag)
{
    if (*flag == 0) return;
    int node = blockIdx.x * (blockDim.x >> 6) + (threadIdx.x >> 6);
    int lane = threadIdx.x & 63;
    if (node >= NODES) return;

    float ps[2] = {0.f, 0.f}, pd[2] = {0.f, 0.f};
    const float* row = h + (size_t)node * HF;
    for (int idx = lane; idx < HF; idx += WAVE) {
        int hd = idx / F;
        float v = row[idx];
        ps[hd] += v * att_s[idx];
        pd[hd] += v * att_d[idx];
    }
#pragma unroll
    for (int off = 32; off; off >>= 1) {
        ps[0] += __shfl_xor(ps[0], off);
        ps[1] += __shfl_xor(ps[1], off);
        pd[0] += __shfl_xor(pd[0], off);
        pd[1] += __shfl_xor(pd[1], off);
    }
    int Hh = HF / F;
    if (lane == 0) {
        for (int hd = 0; hd < Hh; hd++) {
            as_out[node * Hh + hd] = ps[hd];
            ad_out[node * Hh + hd] = pd[hd];
        }
    }
}

// ---------------------------------------------------------------------------
// Post-GEMM GAT aggregation (layers 2/4, single head), +bias (+relu).
// HF=64: 1 edge/iter; HF=32: 2 edges/iter.
// ---------------------------------------------------------------------------
template <int HF, int F, int HH, int RELU>
__global__ __launch_bounds__(256) void gat_aggr(
    const float* __restrict__ hsrc, const float* __restrict__ as_,
    const float* __restrict__ ad_, const int* __restrict__ rowptr,
    const int* __restrict__ csr_src, const float* __restrict__ bias,
    float* __restrict__ out, const int* __restrict__ flag)
{
    if (*flag == 0) return;
    int node = blockIdx.x * (blockDim.x >> 6) + (threadIdx.x >> 6);
    int lane = threadIdx.x & 63;
    if (node >= NODES) return;

    const int beg = rowptr[node], end = rowptr[node + 1];

    float adv[HH], mx[HH], den[HH];
#pragma unroll
    for (int h = 0; h < HH; h++) {
        adv[h] = ad_[node * HH + h];
        mx[h]  = -INFINITY;
        den[h] = 0.f;
    }
    for (int i = beg + lane; i < end; i += WAVE) {
        int s = csr_src[i];
#pragma unroll
        for (int h = 0; h < HH; h++)
            mx[h] = fmaxf(mx[h], lrelu(as_[s * HH + h] + adv[h]));
    }
#pragma unroll
    for (int h = 0; h < HH; h++)
#pragma unroll
        for (int off = 32; off; off >>= 1)
            mx[h] = fmaxf(mx[h], __shfl_xor(mx[h], off));
    for (int i = beg + lane; i < end; i += WAVE) {
        int s = csr_src[i];
#pragma unroll
        for (int h = 0; h < HH; h++)
            den[h] += __expf(lrelu(as_[s * HH + h] + adv[h]) - mx[h]);
    }
#pragma unroll
    for (int h = 0; h < HH; h++)
#pragma unroll
        for (int off = 32; off; off >>= 1)
            den[h] += __shfl_xor(den[h], off);

    constexpr int EPI = (HF < WAVE) ? (WAVE / HF) : 1;
    const int e_sub = (EPI > 1) ? (lane / HF) : 0;
    const int col   = (EPI > 1) ? (lane % HF) : lane;

    float acc = 0.f;
    for (int i = beg + e_sub; i < end; i += EPI) {
        int s = csr_src[i];
        float w[HH];
#pragma unroll
        for (int h = 0; h < HH; h++)
            w[h] = __expf(lrelu(as_[s * HH + h] + adv[h]) - mx[h]);
        acc += hsrc[(size_t)s * HF + col] * w[(F == HF) ? 0 : (col / F)];
    }
    if (EPI > 1) acc += __shfl_xor(acc, HF);
    if (lane < HF) {
        int h = (F == HF) ? 0 : (col / F);
        float v = acc / den[h] + bias[col];
        if (RELU) v = fmaxf(v, 0.f);
        out[(size_t)node * HF + col] = v;
    }
}

// ---------------------------------------------------------------------------
// CSR build kernels (gated on flag != 0)
// ---------------------------------------------------------------------------
__global__ void zero_int(int* __restrict__ p, int n, const int* __restrict__ flag)
{
    if (*flag == 0) return;
    for (int i = blockIdx.x * blockDim.x + threadIdx.x; i < n; i += gridDim.x * blockDim.x)
        p[i] = 0;
}

__global__ void count_deg(const int* __restrict__ ei, int* __restrict__ deg,
                          int E_, int Nn, const int* __restrict__ flag)
{
    if (*flag == 0) return;
    int e = blockIdx.x * blockDim.x + threadIdx.x;
    int tot = E_ + Nn;
    if (e >= tot) return;
    int dst = (e < E_) ? ei[E_ + e] : (e - E_);
    atomicAdd(&deg[dst], 1);
}

__global__ __launch_bounds__(1024) void scan_deg(
    const int* __restrict__ deg, int* __restrict__ rowptr, int n,
    const int* __restrict__ flag)
{
    if (*flag == 0) return;
    __shared__ int temp[1024];
    __shared__ int carry;
    const int t = threadIdx.x;
    if (t == 0) { carry = 0; rowptr[0] = 0; }
    __syncthreads();
    for (int base = 0; base < n; base += 1024) {
        int i = base + t;
        int v = (i < n) ? deg[i] : 0;
        temp[t] = v;
        __syncthreads();
        for (int off = 1; off < 1024; off <<= 1) {
            int x = (t >= off) ? temp[t - off] : 0;
            __syncthreads();
            temp[t] += x;
            __syncthreads();
        }
        if (i < n) rowptr[i + 1] = carry + temp[t];
        __syncthreads();
        if (t == 0) carry += temp[1023];
        __syncthreads();
    }
}

__global__ void copy_int(const int* __restrict__ a, int* __restrict__ b, int n,
                         const int* __restrict__ flag)
{
    if (*flag == 0) return;
    for (int i = blockIdx.x * blockDim.x + threadIdx.x; i < n; i += gridDim.x * blockDim.x)
        b[i] = a[i];
}

__global__ void scatter_edges(const int* __restrict__ ei, int* __restrict__ cursor,
                              int* __restrict__ csr_src, int E_, int Nn,
                              const int* __restrict__ flag)
{
    if (*flag == 0) return;
    int e = blockIdx.x * blockDim.x + threadIdx.x;
    int tot = E_ + Nn;
    if (e >= tot) return;
    int src, dst;
    if (e < E_) { src = ei[e]; dst = ei[E_ + e]; }
    else        { src = e - E_; dst = src; }
    int pos = atomicAdd(&cursor[dst], 1);
    csr_src[pos] = src;
}

// ---------------------------------------------------------------------------
extern "C" void kernel_launch(void* const* d_in, const int* in_sizes, int n_in,
                              void* d_out, int out_size, void* d_ws, size_t ws_size,
                              hipStream_t stream)
{
    const float* x    = (const float*)d_in[0];
    const int*   ei   = (const int*)d_in[1];
    const int*   flag = (const int*)d_in[2];
    const float* W1 = (const float*)d_in[3];
    const float* as1 = (const float*)d_in[4];
    const float* ad1 = (const float*)d_in[5];
    const float* b1 = (const float*)d_in[6];
    const float* W2 = (const float*)d_in[7];
    const float* as2 = (const float*)d_in[8];
    const float* ad2 = (const float*)d_in[9];
    const float* b2 = (const float*)d_in[10];
    const float* W3 = (const float*)d_in[11];
    const float* as3 = (const float*)d_in[12];
    const float* ad3 = (const float*)d_in[13];
    const float* b3 = (const float*)d_in[14];
    const float* W4 = (const float*)d_in[15];
    const float* as4 = (const float*)d_in[16];
    const float* ad4 = (const float*)d_in[17];
    const float* b4 = (const float*)d_in[18];
    const float* el1w = (const float*)d_in[19];
    const float* el1b = (const float*)d_in[20];
    const float* el2w = (const float*)d_in[21];
    const float* el2b = (const float*)d_in[22];
    const float* dl1w = (const float*)d_in[23];
    const float* dl1b = (const float*)d_in[24];
    const float* dl2w = (const float*)d_in[25];
    const float* dl2b = (const float*)d_in[26];

    const int E_   = in_sizes[1] / 2;
    const int Etot = E_ + NODES;

    char* base = (char*)d_ws;
    size_t off = 0;
    auto carve = [&](size_t bytes) -> void* {
        void* p = base + off;
        off = (off + bytes + 255) & ~(size_t)255;
        return p;
    };
    float* T0  = (float*)carve((size_t)NODES * 128 * 4);  // dense-path intermediate / GAT agg buffer
    float* A   = (float*)carve((size_t)NODES * 256 * 4);  // layer1/3 output (relu'd)
    float* T1  = (float*)carve((size_t)NODES * 64 * 4);   // h2 / h4
    float* Bz  = (float*)carve((size_t)NODES * 32 * 4);   // z
    float* asb = (float*)carve((size_t)NODES * 2 * 4);
    float* adb = (float*)carve((size_t)NODES * 2 * 4);
    float* u1s = (float*)carve(2 * 64 * 4);
    float* u1d = (float*)carve(2 * 64 * 4);
    float* u3s = (float*)carve(2 * 32 * 4);
    float* u3d = (float*)carve(2 * 32 * 4);
    int* deg    = (int*)carve((size_t)NODES * 4);
    int* rowptr = (int*)carve((size_t)(NODES + 1) * 4);
    int* cursor = (int*)carve((size_t)NODES * 4);
    int* csr    = (int*)carve((size_t)Etot * 4);
    (void)ws_size; (void)n_in; (void)out_size;

    float* outp = (float*)d_out;
    float* agg  = T0;   // GAT path reuses T0 (paths are mutually exclusive)

    const int nodeBlocks = (NODES + 3) / 4;
    dim3 blk(256);
    const int rowTiles = (NODES + 63) / 64;

    // ---- CSR build (GAT path only) ----
    zero_int<<<(NODES + 255) / 256, 256, 0, stream>>>(deg, NODES, flag);
    count_deg<<<(Etot + 255) / 256, 256, 0, stream>>>(ei, deg, E_, NODES, flag);
    scan_deg<<<1, 1024, 0, stream>>>(deg, rowptr, NODES, flag);
    copy_int<<<(NODES + 255) / 256, 256, 0, stream>>>(rowptr, cursor, NODES, flag);
    scatter_edges<<<(Etot + 255) / 256, 256, 0, stream>>>(ei, cursor, csr, E_, NODES, flag);

    // ---- Layer 1: GAT(64 -> 128 x 2 heads) + ReLU  [aggregate-then-project] ----
    fold_att<<<1, 256, 0, stream>>>(W1, as1, ad1, u1s, u1d, 2, 128, 64, flag);
    att_from_x<64, 2><<<nodeBlocks, blk, 0, stream>>>(x, u1s, u1d, asb, adb, flag);
    gat_aggr_x<64, 2><<<nodeBlocks, blk, 0, stream>>>(x, asb, adb, rowptr, csr, agg, flag);
    gemm_xwt<<<dim3(2, rowTiles, 2), blk, 0, stream>>>(agg, 128, W1, b1, A, 256, NODES, 128, 64, 1, flag, 1);

    // ---- Layer 2: GAT(256 -> 32, 1 head) ----
    gemm_xwt<<<dim3(1, rowTiles, 1), blk, 0, stream>>>(A, 256, W2, nullptr, T1, 32, NODES, 32, 256, 0, flag, 1);
    att_dots<<<nodeBlocks, blk, 0, stream>>>(T1, as2, ad2, asb, adb, 32, 32, flag);
    gat_aggr<32, 32, 1, 0><<<nodeBlocks, blk, 0, stream>>>(T1, asb, adb, rowptr, csr, b2, Bz, flag);

    // ---- Layer 3: GAT(32 -> 128 x 2 heads) + ReLU  [aggregate-then-project] ----
    fold_att<<<1, 256, 0, stream>>>(W3, as3, ad3, u3s, u3d, 2, 128, 32, flag);
    att_from_x<32, 2><<<nodeBlocks, blk, 0, stream>>>(Bz, u3s, u3d, asb, adb, flag);
    gat_aggr_x<32, 2><<<nodeBlocks, blk, 0, stream>>>(Bz, asb, adb, rowptr, csr, agg, flag);
    gemm_xwt<<<dim3(2, rowTiles, 2), blk, 0, stream>>>(agg, 64, W3, b3, A, 256, NODES, 128, 32, 1, flag, 1);

    // ---- Layer 4: GAT(256 -> 64, 1 head) ----
    gemm_xwt<<<dim3(1, rowTiles, 1), blk, 0, stream>>>(A, 256, W4, nullptr, T1, 64, NODES, 64, 256, 0, flag, 1);
    att_dots<<<nodeBlocks, blk, 0, stream>>>(T1, as4, ad4, asb, adb, 64, 64, flag);
    gat_aggr<64, 64, 1, 0><<<nodeBlocks, blk, 0, stream>>>(T1, asb, adb, rowptr, csr, b4, outp, flag);

    // ---- Dense path (use_neighbors == 0) ----
    gemm_xwt<<<dim3(2, rowTiles, 1), blk, 0, stream>>>(x,  64,  el1w, el1b, T0,   128, NODES, 128, 64, 1, flag, 0);
    gemm_xwt<<<dim3(1, rowTiles, 1), blk, 0, stream>>>(T0, 128, el2w, el2b, Bz,   32,  NODES, 32, 128, 0, flag, 0);
    gemm_xwt<<<dim3(2, rowTiles, 1), blk, 0, stream>>>(Bz, 32,  dl1w, dl1b, A,    128, NODES, 128, 32, 1, flag, 0);
    gemm_xwt<<<dim3(1, rowTiles, 1), blk, 0, stream>>>(A,  128, dl2w, dl2b, outp, 64,  NODES, 64, 128, 0, flag, 0);
}

// Round 3
// 487.440 us; speedup vs baseline: 1.2608x; 1.2173x over previous
//
#include <hip/hip_runtime.h>
#include <hip/hip_bf16.h>
#include <math.h>

#define NODES 30000
#define WAVE 64

static __device__ __forceinline__ float lrelu(float x) {
    return (x > 0.f) ? x : 0.2f * x;
}

// ---------------------------------------------------------------------------
// GEMM: out[n, z*M + m] = X[n, z*K + k] @ W[z*M + m, k]^T  (+bias, opt relu)
// ---------------------------------------------------------------------------
__global__ __launch_bounds__(256) void gemm_xwt(
    const float* __restrict__ X, int lda, const float* __restrict__ W,
    const float* __restrict__ bias, float* __restrict__ out, int ldc,
    int Nrows, int M, int K, int relu,
    const int* __restrict__ flag, int wantFlag)
{
    if (((*flag != 0) ? 1 : 0) != wantFlag) return;

    const int z = blockIdx.z;
    X += (size_t)z * K;
    W += (size_t)z * M * K;
    if (bias) bias += (size_t)z * M;
    out += (size_t)z * M;

    __shared__ float As[16][68];
    __shared__ float Bs[16][68];

    const int t  = threadIdx.x;
    const int tx = t & 15;
    const int ty = t >> 4;
    const int rowBase = blockIdx.y * 64;
    const int colBase = blockIdx.x * 64;

    float acc[4][4];
#pragma unroll
    for (int i = 0; i < 4; i++)
#pragma unroll
        for (int j = 0; j < 4; j++) acc[i][j] = 0.f;

    const int r_ld = t >> 2;
    const int k_ld = (t & 3) * 4;

    for (int kt = 0; kt < K; kt += 16) {
        float4 av = make_float4(0.f, 0.f, 0.f, 0.f);
        int grow = rowBase + r_ld;
        if (grow < Nrows)
            av = *reinterpret_cast<const float4*>(&X[(size_t)grow * lda + kt + k_ld]);
        As[k_ld + 0][r_ld] = av.x;
        As[k_ld + 1][r_ld] = av.y;
        As[k_ld + 2][r_ld] = av.z;
        As[k_ld + 3][r_ld] = av.w;
        float4 bv = make_float4(0.f, 0.f, 0.f, 0.f);
        int gm = colBase + r_ld;
        if (gm < M)
            bv = *reinterpret_cast<const float4*>(&W[(size_t)gm * K + kt + k_ld]);
        Bs[k_ld + 0][r_ld] = bv.x;
        Bs[k_ld + 1][r_ld] = bv.y;
        Bs[k_ld + 2][r_ld] = bv.z;
        Bs[k_ld + 3][r_ld] = bv.w;
        __syncthreads();

#pragma unroll
        for (int kk = 0; kk < 16; ++kk) {
            const float4 a = *reinterpret_cast<const float4*>(&As[kk][ty * 4]);
            const float4 b = *reinterpret_cast<const float4*>(&Bs[kk][tx * 4]);
            acc[0][0] += a.x * b.x; acc[0][1] += a.x * b.y; acc[0][2] += a.x * b.z; acc[0][3] += a.x * b.w;
            acc[1][0] += a.y * b.x; acc[1][1] += a.y * b.y; acc[1][2] += a.y * b.z; acc[1][3] += a.y * b.w;
            acc[2][0] += a.z * b.x; acc[2][1] += a.z * b.y; acc[2][2] += a.z * b.z; acc[2][3] += a.z * b.w;
            acc[3][0] += a.w * b.x; acc[3][1] += a.w * b.y; acc[3][2] += a.w * b.z; acc[3][3] += a.w * b.w;
        }
        __syncthreads();
    }

#pragma unroll
    for (int i = 0; i < 4; i++) {
        int row = rowBase + ty * 4 + i;
        if (row >= Nrows) continue;
        int col0 = colBase + tx * 4;
        if (col0 >= M) continue;
        float4 v = make_float4(acc[i][0], acc[i][1], acc[i][2], acc[i][3]);
        if (bias) {
            v.x += bias[col0 + 0]; v.y += bias[col0 + 1];
            v.z += bias[col0 + 2]; v.w += bias[col0 + 3];
        }
        if (relu) {
            v.x = fmaxf(v.x, 0.f); v.y = fmaxf(v.y, 0.f);
            v.z = fmaxf(v.z, 0.f); v.w = fmaxf(v.w, 0.f);
        }
        *reinterpret_cast<float4*>(&out[(size_t)row * ldc + col0]) = v;
    }
}

// ---------------------------------------------------------------------------
// Fold attention vectors into input space: u[h,k] = sum_f att[h,f] * W[h*F+f, k]
// ---------------------------------------------------------------------------
__global__ void fold_att(const float* __restrict__ W, const float* __restrict__ as_,
                         const float* __restrict__ ad_, float* __restrict__ us,
                         float* __restrict__ ud, int Hh, int F, int K,
                         const int* __restrict__ flag)
{
    if (*flag == 0) return;
    int t = blockIdx.x * blockDim.x + threadIdx.x;
    int tot = 2 * Hh * K;
    if (t >= tot) return;
    int sel = t / (Hh * K);
    int r = t % (Hh * K);
    int h = r / K, k = r % K;
    const float* att = sel ? ad_ : as_;
    float s = 0.f;
    for (int f = 0; f < F; f++)
        s += att[h * F + f] * W[(size_t)(h * F + f) * K + k];
    (sel ? ud : us)[r] = s;
}

// ---------------------------------------------------------------------------
// a_s[n,h] = feat[n,:] . u_s[h,:]  (and a_d).  64/K nodes per wave.
// ---------------------------------------------------------------------------
template <int K, int HH>
__global__ __launch_bounds__(256) void att_from_x(
    const float* __restrict__ xin, const float* __restrict__ us,
    const float* __restrict__ ud, float* __restrict__ as_out,
    float* __restrict__ ad_out, const int* __restrict__ flag)
{
    if (*flag == 0) return;
    constexpr int NPW = WAVE / K;
    const int wid  = threadIdx.x >> 6;
    const int lane = threadIdx.x & 63;
    const int sub  = lane / K;
    const int col  = lane % K;
    const int node = (blockIdx.x * 4 + wid) * NPW + sub;

    float v = 0.f;
    if (node < NODES) v = xin[(size_t)node * K + col];
    float ps[HH], pd[HH];
#pragma unroll
    for (int h = 0; h < HH; h++) {
        ps[h] = v * us[h * K + col];
        pd[h] = v * ud[h * K + col];
    }
#pragma unroll
    for (int off = K / 2; off; off >>= 1) {
#pragma unroll
        for (int h = 0; h < HH; h++) {
            ps[h] += __shfl_xor(ps[h], off);
            pd[h] += __shfl_xor(pd[h], off);
        }
    }
    if (col == 0 && node < NODES) {
#pragma unroll
        for (int h = 0; h < HH; h++) {
            as_out[node * HH + h] = ps[h];
            ad_out[node * HH + h] = pd[h];
        }
    }
}

// ---------------------------------------------------------------------------
// Edge-parallel gather of a_s[src] into contiguous per-edge buffer eb.
// ---------------------------------------------------------------------------
template <int HH>
__global__ void gather_e(const float* __restrict__ as_, const int* __restrict__ csr_src,
                         float* __restrict__ eb, int Etot, const int* __restrict__ flag)
{
    if (*flag == 0) return;
    int i = blockIdx.x * blockDim.x + threadIdx.x;
    if (i >= Etot) return;
    int s = csr_src[i];
    if (HH == 1) {
        eb[i] = as_[s];
    } else {
        float2 v = *reinterpret_cast<const float2*>(&as_[s * 2]);
        *reinterpret_cast<float2*>(&eb[(size_t)i * 2]) = v;
    }
}

// ---------------------------------------------------------------------------
// Fused GAT aggregation of RAW features (layers 1/3, aggregate-then-project):
// agg[n, h*K + k] = softmax-weighted sum of xin[src, k].
// One wave per dst node. Gather phase: 64/(K/4) edges per iter, float4/lane.
// ---------------------------------------------------------------------------
template <int K, int HH>
__global__ __launch_bounds__(256) void gat_aggr_x(
    const float* __restrict__ xin, const float* __restrict__ eb,
    const float* __restrict__ ad_, const int* __restrict__ rowptr,
    const int* __restrict__ csr_src, float* __restrict__ agg,
    const int* __restrict__ flag)
{
    if (*flag == 0) return;
    const int node = blockIdx.x * 4 + (threadIdx.x >> 6);
    const int lane = threadIdx.x & 63;
    if (node >= NODES) return;

    const int beg = rowptr[node], end = rowptr[node + 1];

    float adv[HH], mx[HH], den[HH];
#pragma unroll
    for (int h = 0; h < HH; h++) {
        adv[h] = ad_[node * HH + h];
        mx[h]  = -1e30f;
        den[h] = 0.f;
    }
    // coalesced max over eb segment
    for (int i = beg + lane; i < end; i += WAVE) {
#pragma unroll
        for (int h = 0; h < HH; h++)
            mx[h] = fmaxf(mx[h], lrelu(eb[(size_t)i * HH + h] + adv[h]));
    }
#pragma unroll
    for (int h = 0; h < HH; h++)
#pragma unroll
        for (int off = 32; off; off >>= 1)
            mx[h] = fmaxf(mx[h], __shfl_xor(mx[h], off));
    // coalesced denom
    for (int i = beg + lane; i < end; i += WAVE) {
#pragma unroll
        for (int h = 0; h < HH; h++)
            den[h] += __expf(lrelu(eb[(size_t)i * HH + h] + adv[h]) - mx[h]);
    }
#pragma unroll
    for (int h = 0; h < HH; h++)
#pragma unroll
        for (int off = 32; off; off >>= 1)
            den[h] += __shfl_xor(den[h], off);
    float rden[HH];
#pragma unroll
    for (int h = 0; h < HH; h++) rden[h] = 1.f / den[h];

    // gather phase: multiple edges per iteration, float4 per lane
    constexpr int LPG = K / 4;          // lanes per edge-group
    constexpr int GR  = WAVE / LPG;     // edges in flight per iter
    const int esub = lane / LPG;
    const int c4   = lane % LPG;

    float4 acc[HH];
#pragma unroll
    for (int h = 0; h < HH; h++) acc[h] = make_float4(0.f, 0.f, 0.f, 0.f);

    for (int i = beg + esub; i < end; i += GR) {
        int s = csr_src[i];
        float w[HH];
#pragma unroll
        for (int h = 0; h < HH; h++)
            w[h] = __expf(lrelu(eb[(size_t)i * HH + h] + adv[h]) - mx[h]);
        float4 xv = *reinterpret_cast<const float4*>(&xin[(size_t)s * K + c4 * 4]);
#pragma unroll
        for (int h = 0; h < HH; h++) {
            acc[h].x += xv.x * w[h];
            acc[h].y += xv.y * w[h];
            acc[h].z += xv.z * w[h];
            acc[h].w += xv.w * w[h];
        }
    }
#pragma unroll
    for (int off = LPG; off < WAVE; off <<= 1) {
#pragma unroll
        for (int h = 0; h < HH; h++) {
            acc[h].x += __shfl_xor(acc[h].x, off);
            acc[h].y += __shfl_xor(acc[h].y, off);
            acc[h].z += __shfl_xor(acc[h].z, off);
            acc[h].w += __shfl_xor(acc[h].w, off);
        }
    }
    if (esub == 0) {
#pragma unroll
        for (int h = 0; h < HH; h++) {
            float4 o = make_float4(acc[h].x * rden[h], acc[h].y * rden[h],
                                   acc[h].z * rden[h], acc[h].w * rden[h]);
            *reinterpret_cast<float4*>(&agg[(size_t)node * (HH * K) + h * K + c4 * 4]) = o;
        }
    }
}

// ---------------------------------------------------------------------------
// Fused GAT aggregation of PROJECTED features (layers 2/4, single head),
// +bias (+relu). Same multi-edge float4 gather structure.
// ---------------------------------------------------------------------------
template <int HF, int RELU>
__global__ __launch_bounds__(256) void gat_aggr_h(
    const float* __restrict__ hsrc, const float* __restrict__ eb,
    const float* __restrict__ ad_, const int* __restrict__ rowptr,
    const int* __restrict__ csr_src, const float* __restrict__ bias,
    float* __restrict__ out, const int* __restrict__ flag)
{
    if (*flag == 0) return;
    const int node = blockIdx.x * 4 + (threadIdx.x >> 6);
    const int lane = threadIdx.x & 63;
    if (node >= NODES) return;

    const int beg = rowptr[node], end = rowptr[node + 1];
    const float adv = ad_[node];

    float mx = -1e30f, den = 0.f;
    for (int i = beg + lane; i < end; i += WAVE)
        mx = fmaxf(mx, lrelu(eb[i] + adv));
#pragma unroll
    for (int off = 32; off; off >>= 1)
        mx = fmaxf(mx, __shfl_xor(mx, off));
    for (int i = beg + lane; i < end; i += WAVE)
        den += __expf(lrelu(eb[i] + adv) - mx);
#pragma unroll
    for (int off = 32; off; off >>= 1)
        den += __shfl_xor(den, off);
    const float rden = 1.f / den;

    constexpr int LPG = HF / 4;
    constexpr int GR  = WAVE / LPG;
    const int esub = lane / LPG;
    const int c4   = lane % LPG;

    float4 acc = make_float4(0.f, 0.f, 0.f, 0.f);
    for (int i = beg + esub; i < end; i += GR) {
        int s = csr_src[i];
        float w = __expf(lrelu(eb[i] + adv) - mx);
        float4 hv = *reinterpret_cast<const float4*>(&hsrc[(size_t)s * HF + c4 * 4]);
        acc.x += hv.x * w; acc.y += hv.y * w; acc.z += hv.z * w; acc.w += hv.w * w;
    }
#pragma unroll
    for (int off = LPG; off < WAVE; off <<= 1) {
        acc.x += __shfl_xor(acc.x, off);
        acc.y += __shfl_xor(acc.y, off);
        acc.z += __shfl_xor(acc.z, off);
        acc.w += __shfl_xor(acc.w, off);
    }
    if (esub == 0) {
        float4 bv = *reinterpret_cast<const float4*>(&bias[c4 * 4]);
        float4 o = make_float4(acc.x * rden + bv.x, acc.y * rden + bv.y,
                               acc.z * rden + bv.z, acc.w * rden + bv.w);
        if (RELU) {
            o.x = fmaxf(o.x, 0.f); o.y = fmaxf(o.y, 0.f);
            o.z = fmaxf(o.z, 0.f); o.w = fmaxf(o.w, 0.f);
        }
        *reinterpret_cast<float4*>(&out[(size_t)node * HF + c4 * 4]) = o;
    }
}

// ---------------------------------------------------------------------------
// CSR build kernels
// ---------------------------------------------------------------------------
__global__ void zero_int(int* __restrict__ p, int n, const int* __restrict__ flag)
{
    if (*flag == 0) return;
    for (int i = blockIdx.x * blockDim.x + threadIdx.x; i < n; i += gridDim.x * blockDim.x)
        p[i] = 0;
}

__global__ void count_deg(const int* __restrict__ ei, int* __restrict__ deg,
                          int E_, int Nn, const int* __restrict__ flag)
{
    if (*flag == 0) return;
    int e = blockIdx.x * blockDim.x + threadIdx.x;
    int tot = E_ + Nn;
    if (e >= tot) return;
    int dst = (e < E_) ? ei[E_ + e] : (e - E_);
    atomicAdd(&deg[dst], 1);
}

// 1 block / 1024 threads: per-thread serial chunk + one 1024-wide scan.
__global__ __launch_bounds__(1024) void scan_deg(
    const int* __restrict__ deg, int* __restrict__ rowptr, int n,
    const int* __restrict__ flag)
{
    if (*flag == 0) return;
    __shared__ int sums[1024];
    const int t = threadIdx.x;
    const int CH = (n + 1023) >> 10;
    const int base = t * CH;

    int s = 0;
    for (int j = 0; j < CH; j++) {
        int i = base + j;
        if (i < n) s += deg[i];
    }
    sums[t] = s;
    __syncthreads();
    for (int off = 1; off < 1024; off <<= 1) {
        int v = (t >= off) ? sums[t - off] : 0;
        __syncthreads();
        sums[t] += v;
        __syncthreads();
    }
    int run = sums[t] - s;  // exclusive offset
    if (t == 0) rowptr[0] = 0;
    for (int j = 0; j < CH; j++) {
        int i = base + j;
        if (i < n) {
            run += deg[i];
            rowptr[i + 1] = run;
        }
    }
}

__global__ void copy_int(const int* __restrict__ a, int* __restrict__ b, int n,
                         const int* __restrict__ flag)
{
    if (*flag == 0) return;
    for (int i = blockIdx.x * blockDim.x + threadIdx.x; i < n; i += gridDim.x * blockDim.x)
        b[i] = a[i];
}

__global__ void scatter_edges(const int* __restrict__ ei, int* __restrict__ cursor,
                              int* __restrict__ csr_src, int E_, int Nn,
                              const int* __restrict__ flag)
{
    if (*flag == 0) return;
    int e = blockIdx.x * blockDim.x + threadIdx.x;
    int tot = E_ + Nn;
    if (e >= tot) return;
    int src, dst;
    if (e < E_) { src = ei[e]; dst = ei[E_ + e]; }
    else        { src = e - E_; dst = src; }
    int pos = atomicAdd(&cursor[dst], 1);
    csr_src[pos] = src;
}

// ---------------------------------------------------------------------------
extern "C" void kernel_launch(void* const* d_in, const int* in_sizes, int n_in,
                              void* d_out, int out_size, void* d_ws, size_t ws_size,
                              hipStream_t stream)
{
    const float* x    = (const float*)d_in[0];
    const int*   ei   = (const int*)d_in[1];
    const int*   flag = (const int*)d_in[2];
    const float* W1 = (const float*)d_in[3];
    const float* as1 = (const float*)d_in[4];
    const float* ad1 = (const float*)d_in[5];
    const float* b1 = (const float*)d_in[6];
    const float* W2 = (const float*)d_in[7];
    const float* as2 = (const float*)d_in[8];
    const float* ad2 = (const float*)d_in[9];
    const float* b2 = (const float*)d_in[10];
    const float* W3 = (const float*)d_in[11];
    const float* as3 = (const float*)d_in[12];
    const float* ad3 = (const float*)d_in[13];
    const float* b3 = (const float*)d_in[14];
    const float* W4 = (const float*)d_in[15];
    const float* as4 = (const float*)d_in[16];
    const float* ad4 = (const float*)d_in[17];
    const float* b4 = (const float*)d_in[18];
    const float* el1w = (const float*)d_in[19];
    const float* el1b = (const float*)d_in[20];
    const float* el2w = (const float*)d_in[21];
    const float* el2b = (const float*)d_in[22];
    const float* dl1w = (const float*)d_in[23];
    const float* dl1b = (const float*)d_in[24];
    const float* dl2w = (const float*)d_in[25];
    const float* dl2b = (const float*)d_in[26];

    const int E_   = in_sizes[1] / 2;
    const int Etot = E_ + NODES;

    char* base = (char*)d_ws;
    size_t off = 0;
    auto carve = [&](size_t bytes) -> void* {
        void* p = base + off;
        off = (off + bytes + 255) & ~(size_t)255;
        return p;
    };
    float* T0  = (float*)carve((size_t)NODES * 128 * 4);  // dense intermediate / GAT agg buffer
    float* A   = (float*)carve((size_t)NODES * 256 * 4);  // layer1/3 output (relu'd)
    float* T1  = (float*)carve((size_t)NODES * 64 * 4);   // h2 / h4
    float* Bz  = (float*)carve((size_t)NODES * 32 * 4);   // z
    float* asb = (float*)carve((size_t)NODES * 2 * 4);
    float* adb = (float*)carve((size_t)NODES * 2 * 4);
    float* eb  = (float*)carve((size_t)Etot * 2 * 4);     // per-edge a_s buffer
    float* u1s = (float*)carve(2 * 64 * 4);
    float* u1d = (float*)carve(2 * 64 * 4);
    float* u3s = (float*)carve(2 * 32 * 4);
    float* u3d = (float*)carve(2 * 32 * 4);
    int* deg    = (int*)carve((size_t)NODES * 4);
    int* rowptr = (int*)carve((size_t)(NODES + 1) * 4);
    int* cursor = (int*)carve((size_t)NODES * 4);
    int* csr    = (int*)carve((size_t)Etot * 4);
    (void)ws_size; (void)n_in; (void)out_size;

    float* outp = (float*)d_out;
    float* agg  = T0;

    const int nodeBlocks = (NODES + 3) / 4;
    const int edgeBlocks = (Etot + 255) / 256;
    dim3 blk(256);
    const int rowTiles = (NODES + 63) / 64;

    // ---- CSR build ----
    zero_int<<<(NODES + 255) / 256, 256, 0, stream>>>(deg, NODES, flag);
    count_deg<<<edgeBlocks, 256, 0, stream>>>(ei, deg, E_, NODES, flag);
    scan_deg<<<1, 1024, 0, stream>>>(deg, rowptr, NODES, flag);
    copy_int<<<(NODES + 255) / 256, 256, 0, stream>>>(rowptr, cursor, NODES, flag);
    scatter_edges<<<edgeBlocks, 256, 0, stream>>>(ei, cursor, csr, E_, NODES, flag);

    // ---- Layer 1: GAT(64 -> 128 x 2 heads) + ReLU  [aggregate-then-project] ----
    fold_att<<<1, 256, 0, stream>>>(W1, as1, ad1, u1s, u1d, 2, 128, 64, flag);
    att_from_x<64, 2><<<nodeBlocks, blk, 0, stream>>>(x, u1s, u1d, asb, adb, flag);
    gather_e<2><<<edgeBlocks, 256, 0, stream>>>(asb, csr, eb, Etot, flag);
    gat_aggr_x<64, 2><<<nodeBlocks, blk, 0, stream>>>(x, eb, adb, rowptr, csr, agg, flag);
    gemm_xwt<<<dim3(2, rowTiles, 2), blk, 0, stream>>>(agg, 128, W1, b1, A, 256, NODES, 128, 64, 1, flag, 1);

    // ---- Layer 2: GAT(256 -> 32, 1 head) ----
    gemm_xwt<<<dim3(1, rowTiles, 1), blk, 0, stream>>>(A, 256, W2, nullptr, T1, 32, NODES, 32, 256, 0, flag, 1);
    att_from_x<32, 1><<<(NODES + 7) / 8, blk, 0, stream>>>(T1, as2, ad2, asb, adb, flag);
    gather_e<1><<<edgeBlocks, 256, 0, stream>>>(asb, csr, eb, Etot, flag);
    gat_aggr_h<32, 0><<<nodeBlocks, blk, 0, stream>>>(T1, eb, adb, rowptr, csr, b2, Bz, flag);

    // ---- Layer 3: GAT(32 -> 128 x 2 heads) + ReLU  [aggregate-then-project] ----
    fold_att<<<1, 256, 0, stream>>>(W3, as3, ad3, u3s, u3d, 2, 128, 32, flag);
    att_from_x<32, 2><<<(NODES + 7) / 8, blk, 0, stream>>>(Bz, u3s, u3d, asb, adb, flag);
    gather_e<2><<<edgeBlocks, 256, 0, stream>>>(asb, csr, eb, Etot, flag);
    gat_aggr_x<32, 2><<<nodeBlocks, blk, 0, stream>>>(Bz, eb, adb, rowptr, csr, agg, flag);
    gemm_xwt<<<dim3(2, rowTiles, 2), blk, 0, stream>>>(agg, 64, W3, b3, A, 256, NODES, 128, 32, 1, flag, 1);

    // ---- Layer 4: GAT(256 -> 64, 1 head) ----
    gemm_xwt<<<dim3(1, rowTiles, 1), blk, 0, stream>>>(A, 256, W4, nullptr, T1, 64, NODES, 64, 256, 0, flag, 1);
    att_from_x<64, 1><<<nodeBlocks, blk, 0, stream>>>(T1, as4, ad4, asb, adb, flag);
    gather_e<1><<<edgeBlocks, 256, 0, stream>>>(asb, csr, eb, Etot, flag);
    gat_aggr_h<64, 0><<<nodeBlocks, blk, 0, stream>>>(T1, eb, adb, rowptr, csr, b4, outp, flag);

    // ---- Dense path (use_neighbors == 0) ----
    gemm_xwt<<<dim3(2, rowTiles, 1), blk, 0, stream>>>(x,  64,  el1w, el1b, T0,   128, NODES, 128, 64, 1, flag, 0);
    gemm_xwt<<<dim3(1, rowTiles, 1), blk, 0, stream>>>(T0, 128, el2w, el2b, Bz,   32,  NODES, 32, 128, 0, flag, 0);
    gemm_xwt<<<dim3(2, rowTiles, 1), blk, 0, stream>>>(Bz, 32,  dl1w, dl1b, A,    128, NODES, 128, 32, 1, flag, 0);
    gemm_xwt<<<dim3(1, rowTiles, 1), blk, 0, stream>>>(A,  128, dl2w, dl2b, outp, 64,  NODES, 64, 128, 0, flag, 0);
}

// Round 5
// 401.235 us; speedup vs baseline: 1.5317x; 1.2148x over previous
//
#include <hip/hip_runtime.h>
#include <hip/hip_bf16.h>
#include <math.h>

#define NODES 30000
#define WAVE 64
#define SCAN_T 1024
#define SCAN_CH 32
#define SCAN_CAP (SCAN_T * SCAN_CH)   // 32768 >= NODES, enables branchless scan

static __device__ __forceinline__ float lrelu(float x) {
    return (x > 0.f) ? x : 0.2f * x;
}

// ---------------------------------------------------------------------------
// GEMM: out[n, z*M + m] = X[n, z*K + k] @ W[z*M + m, k]^T  (+bias, opt relu)
// ---------------------------------------------------------------------------
__global__ __launch_bounds__(256) void gemm_xwt(
    const float* __restrict__ X, int lda, const float* __restrict__ W,
    const float* __restrict__ bias, float* __restrict__ out, int ldc,
    int Nrows, int M, int K, int relu,
    const int* __restrict__ flag, int wantFlag)
{
    if (((*flag != 0) ? 1 : 0) != wantFlag) return;

    const int z = blockIdx.z;
    X += (size_t)z * K;
    W += (size_t)z * M * K;
    if (bias) bias += (size_t)z * M;
    out += (size_t)z * M;

    __shared__ float As[16][68];
    __shared__ float Bs[16][68];

    const int t  = threadIdx.x;
    const int tx = t & 15;
    const int ty = t >> 4;
    const int rowBase = blockIdx.y * 64;
    const int colBase = blockIdx.x * 64;

    float acc[4][4];
#pragma unroll
    for (int i = 0; i < 4; i++)
#pragma unroll
        for (int j = 0; j < 4; j++) acc[i][j] = 0.f;

    const int r_ld = t >> 2;
    const int k_ld = (t & 3) * 4;

    for (int kt = 0; kt < K; kt += 16) {
        float4 av = make_float4(0.f, 0.f, 0.f, 0.f);
        int grow = rowBase + r_ld;
        if (grow < Nrows)
            av = *reinterpret_cast<const float4*>(&X[(size_t)grow * lda + kt + k_ld]);
        As[k_ld + 0][r_ld] = av.x;
        As[k_ld + 1][r_ld] = av.y;
        As[k_ld + 2][r_ld] = av.z;
        As[k_ld + 3][r_ld] = av.w;
        float4 bv = make_float4(0.f, 0.f, 0.f, 0.f);
        int gm = colBase + r_ld;
        if (gm < M)
            bv = *reinterpret_cast<const float4*>(&W[(size_t)gm * K + kt + k_ld]);
        Bs[k_ld + 0][r_ld] = bv.x;
        Bs[k_ld + 1][r_ld] = bv.y;
        Bs[k_ld + 2][r_ld] = bv.z;
        Bs[k_ld + 3][r_ld] = bv.w;
        __syncthreads();

#pragma unroll
        for (int kk = 0; kk < 16; ++kk) {
            const float4 a = *reinterpret_cast<const float4*>(&As[kk][ty * 4]);
            const float4 b = *reinterpret_cast<const float4*>(&Bs[kk][tx * 4]);
            acc[0][0] += a.x * b.x; acc[0][1] += a.x * b.y; acc[0][2] += a.x * b.z; acc[0][3] += a.x * b.w;
            acc[1][0] += a.y * b.x; acc[1][1] += a.y * b.y; acc[1][2] += a.y * b.z; acc[1][3] += a.y * b.w;
            acc[2][0] += a.z * b.x; acc[2][1] += a.z * b.y; acc[2][2] += a.z * b.z; acc[2][3] += a.z * b.w;
            acc[3][0] += a.w * b.x; acc[3][1] += a.w * b.y; acc[3][2] += a.w * b.z; acc[3][3] += a.w * b.w;
        }
        __syncthreads();
    }

#pragma unroll
    for (int i = 0; i < 4; i++) {
        int row = rowBase + ty * 4 + i;
        if (row >= Nrows) continue;
        int col0 = colBase + tx * 4;
        if (col0 >= M) continue;
        float4 v = make_float4(acc[i][0], acc[i][1], acc[i][2], acc[i][3]);
        if (bias) {
            v.x += bias[col0 + 0]; v.y += bias[col0 + 1];
            v.z += bias[col0 + 2]; v.w += bias[col0 + 3];
        }
        if (relu) {
            v.x = fmaxf(v.x, 0.f); v.y = fmaxf(v.y, 0.f);
            v.z = fmaxf(v.z, 0.f); v.w = fmaxf(v.w, 0.f);
        }
        *reinterpret_cast<float4*>(&out[(size_t)row * ldc + col0]) = v;
    }
}

// ---------------------------------------------------------------------------
// Fold attention vectors into input space: u[h,k] = sum_f att[h,f] * W[h*F+f, k]
// One block per (sel, h); 256 threads as (f-group, k); fully unrolled loads.
// ---------------------------------------------------------------------------
template <int HH, int F, int K>
__global__ __launch_bounds__(256) void fold_att(
    const float* __restrict__ W, const float* __restrict__ as_,
    const float* __restrict__ ad_, float* __restrict__ us,
    float* __restrict__ ud, const int* __restrict__ flag)
{
    if (*flag == 0) return;
    const int b   = blockIdx.x;        // 0 .. 2*HH-1
    const int sel = b / HH;
    const int h   = b % HH;
    const float* att = sel ? ad_ : as_;
    float* uo = sel ? ud : us;

    constexpr int NG = 256 / K;        // f-groups
    const int k  = threadIdx.x % K;
    const int fg = threadIdx.x / K;

    float s = 0.f;
#pragma unroll
    for (int f = fg; f < F; f += NG)
        s += att[h * F + f] * W[(size_t)(h * F + f) * K + k];

    __shared__ float red[256];
    red[threadIdx.x] = s;
    __syncthreads();
    if (fg == 0) {
        float tot = s;
#pragma unroll
        for (int g = 1; g < NG; g++) tot += red[g * K + k];
        uo[h * K + k] = tot;
    }
}

// ---------------------------------------------------------------------------
// a_s[n,h] = feat[n,:] . u_s[h,:]  (and a_d).  64/K nodes per wave.
// ---------------------------------------------------------------------------
template <int K, int HH>
__global__ __launch_bounds__(256) void att_from_x(
    const float* __restrict__ xin, const float* __restrict__ us,
    const float* __restrict__ ud, float* __restrict__ as_out,
    float* __restrict__ ad_out, const int* __restrict__ flag)
{
    if (*flag == 0) return;
    constexpr int NPW = WAVE / K;
    const int wid  = threadIdx.x >> 6;
    const int lane = threadIdx.x & 63;
    const int sub  = lane / K;
    const int col  = lane % K;
    const int node = (blockIdx.x * 4 + wid) * NPW + sub;

    float v = 0.f;
    if (node < NODES) v = xin[(size_t)node * K + col];
    float ps[HH], pd[HH];
#pragma unroll
    for (int h = 0; h < HH; h++) {
        ps[h] = v * us[h * K + col];
        pd[h] = v * ud[h * K + col];
    }
#pragma unroll
    for (int off = K / 2; off; off >>= 1) {
#pragma unroll
        for (int h = 0; h < HH; h++) {
            ps[h] += __shfl_xor(ps[h], off);
            pd[h] += __shfl_xor(pd[h], off);
        }
    }
    if (col == 0 && node < NODES) {
#pragma unroll
        for (int h = 0; h < HH; h++) {
            as_out[node * HH + h] = ps[h];
            ad_out[node * HH + h] = pd[h];
        }
    }
}

// ---------------------------------------------------------------------------
// Edge-parallel gather of a_s[src] into contiguous per-edge buffer eb.
// ---------------------------------------------------------------------------
template <int HH>
__global__ void gather_e(const float* __restrict__ as_, const int* __restrict__ csr_src,
                         float* __restrict__ eb, int Etot, const int* __restrict__ flag)
{
    if (*flag == 0) return;
    int i = blockIdx.x * blockDim.x + threadIdx.x;
    if (i >= Etot) return;
    int s = csr_src[i];
    if (HH == 1) {
        eb[i] = as_[s];
    } else {
        float2 v = *reinterpret_cast<const float2*>(&as_[s * 2]);
        *reinterpret_cast<float2*>(&eb[(size_t)i * 2]) = v;
    }
}

// ---------------------------------------------------------------------------
// Fused GAT aggregation of RAW features (layers 1/3, aggregate-then-project).
// ---------------------------------------------------------------------------
template <int K, int HH>
__global__ __launch_bounds__(256) void gat_aggr_x(
    const float* __restrict__ xin, const float* __restrict__ eb,
    const float* __restrict__ ad_, const int* __restrict__ rowptr,
    const int* __restrict__ csr_src, float* __restrict__ agg,
    const int* __restrict__ flag)
{
    if (*flag == 0) return;
    const int node = blockIdx.x * 4 + (threadIdx.x >> 6);
    const int lane = threadIdx.x & 63;
    if (node >= NODES) return;

    const int beg = rowptr[node], end = rowptr[node + 1];

    float adv[HH], mx[HH], den[HH];
#pragma unroll
    for (int h = 0; h < HH; h++) {
        adv[h] = ad_[node * HH + h];
        mx[h]  = -1e30f;
        den[h] = 0.f;
    }
    for (int i = beg + lane; i < end; i += WAVE) {
#pragma unroll
        for (int h = 0; h < HH; h++)
            mx[h] = fmaxf(mx[h], lrelu(eb[(size_t)i * HH + h] + adv[h]));
    }
#pragma unroll
    for (int h = 0; h < HH; h++)
#pragma unroll
        for (int off = 32; off; off >>= 1)
            mx[h] = fmaxf(mx[h], __shfl_xor(mx[h], off));
    for (int i = beg + lane; i < end; i += WAVE) {
#pragma unroll
        for (int h = 0; h < HH; h++)
            den[h] += __expf(lrelu(eb[(size_t)i * HH + h] + adv[h]) - mx[h]);
    }
#pragma unroll
    for (int h = 0; h < HH; h++)
#pragma unroll
        for (int off = 32; off; off >>= 1)
            den[h] += __shfl_xor(den[h], off);
    float rden[HH];
#pragma unroll
    for (int h = 0; h < HH; h++) rden[h] = 1.f / den[h];

    constexpr int LPG = K / 4;
    constexpr int GR  = WAVE / LPG;
    const int esub = lane / LPG;
    const int c4   = lane % LPG;

    float4 acc[HH];
#pragma unroll
    for (int h = 0; h < HH; h++) acc[h] = make_float4(0.f, 0.f, 0.f, 0.f);

    for (int i = beg + esub; i < end; i += GR) {
        int s = csr_src[i];
        float w[HH];
#pragma unroll
        for (int h = 0; h < HH; h++)
            w[h] = __expf(lrelu(eb[(size_t)i * HH + h] + adv[h]) - mx[h]);
        float4 xv = *reinterpret_cast<const float4*>(&xin[(size_t)s * K + c4 * 4]);
#pragma unroll
        for (int h = 0; h < HH; h++) {
            acc[h].x += xv.x * w[h];
            acc[h].y += xv.y * w[h];
            acc[h].z += xv.z * w[h];
            acc[h].w += xv.w * w[h];
        }
    }
#pragma unroll
    for (int off = LPG; off < WAVE; off <<= 1) {
#pragma unroll
        for (int h = 0; h < HH; h++) {
            acc[h].x += __shfl_xor(acc[h].x, off);
            acc[h].y += __shfl_xor(acc[h].y, off);
            acc[h].z += __shfl_xor(acc[h].z, off);
            acc[h].w += __shfl_xor(acc[h].w, off);
        }
    }
    if (esub == 0) {
#pragma unroll
        for (int h = 0; h < HH; h++) {
            float4 o = make_float4(acc[h].x * rden[h], acc[h].y * rden[h],
                                   acc[h].z * rden[h], acc[h].w * rden[h]);
            *reinterpret_cast<float4*>(&agg[(size_t)node * (HH * K) + h * K + c4 * 4]) = o;
        }
    }
}

// ---------------------------------------------------------------------------
// Fused GAT aggregation of PROJECTED features (layers 2/4), +bias (+relu).
// ---------------------------------------------------------------------------
template <int HF, int RELU>
__global__ __launch_bounds__(256) void gat_aggr_h(
    const float* __restrict__ hsrc, const float* __restrict__ eb,
    const float* __restrict__ ad_, const int* __restrict__ rowptr,
    const int* __restrict__ csr_src, const float* __restrict__ bias,
    float* __restrict__ out, const int* __restrict__ flag)
{
    if (*flag == 0) return;
    const int node = blockIdx.x * 4 + (threadIdx.x >> 6);
    const int lane = threadIdx.x & 63;
    if (node >= NODES) return;

    const int beg = rowptr[node], end = rowptr[node + 1];
    const float adv = ad_[node];

    float mx = -1e30f, den = 0.f;
    for (int i = beg + lane; i < end; i += WAVE)
        mx = fmaxf(mx, lrelu(eb[i] + adv));
#pragma unroll
    for (int off = 32; off; off >>= 1)
        mx = fmaxf(mx, __shfl_xor(mx, off));
    for (int i = beg + lane; i < end; i += WAVE)
        den += __expf(lrelu(eb[i] + adv) - mx);
#pragma unroll
    for (int off = 32; off; off >>= 1)
        den += __shfl_xor(den, off);
    const float rden = 1.f / den;

    constexpr int LPG = HF / 4;
    constexpr int GR  = WAVE / LPG;
    const int esub = lane / LPG;
    const int c4   = lane % LPG;

    float4 acc = make_float4(0.f, 0.f, 0.f, 0.f);
    for (int i = beg + esub; i < end; i += GR) {
        int s = csr_src[i];
        float w = __expf(lrelu(eb[i] + adv) - mx);
        float4 hv = *reinterpret_cast<const float4*>(&hsrc[(size_t)s * HF + c4 * 4]);
        acc.x += hv.x * w; acc.y += hv.y * w; acc.z += hv.z * w; acc.w += hv.w * w;
    }
#pragma unroll
    for (int off = LPG; off < WAVE; off <<= 1) {
        acc.x += __shfl_xor(acc.x, off);
        acc.y += __shfl_xor(acc.y, off);
        acc.z += __shfl_xor(acc.z, off);
        acc.w += __shfl_xor(acc.w, off);
    }
    if (esub == 0) {
        float4 bv = *reinterpret_cast<const float4*>(&bias[c4 * 4]);
        float4 o = make_float4(acc.x * rden + bv.x, acc.y * rden + bv.y,
                               acc.z * rden + bv.z, acc.w * rden + bv.w);
        if (RELU) {
            o.x = fmaxf(o.x, 0.f); o.y = fmaxf(o.y, 0.f);
            o.z = fmaxf(o.z, 0.f); o.w = fmaxf(o.w, 0.f);
        }
        *reinterpret_cast<float4*>(&out[(size_t)node * HF + c4 * 4]) = o;
    }
}

// ---------------------------------------------------------------------------
// CSR build kernels
// ---------------------------------------------------------------------------
__global__ void zero_int(int* __restrict__ p, int n, const int* __restrict__ flag)
{
    if (*flag == 0) return;
    for (int i = blockIdx.x * blockDim.x + threadIdx.x; i < n; i += gridDim.x * blockDim.x)
        p[i] = 0;
}

__global__ void count_deg(const int* __restrict__ ei, int* __restrict__ deg,
                          int E_, int Nn, const int* __restrict__ flag)
{
    if (*flag == 0) return;
    int e = blockIdx.x * blockDim.x + threadIdx.x;
    int tot = E_ + Nn;
    if (e >= tot) return;
    int dst = (e < E_) ? ei[E_ + e] : (e - E_);
    atomicAdd(&deg[dst], 1);
}

// Branchless single-block scan over SCAN_CAP (deg zero-padded to SCAN_CAP).
// Writes rowptr[0..SCAN_CAP] AND cursor[0..SCAN_CAP-1] (= rowptr[i]).
__global__ __launch_bounds__(SCAN_T) void scan_deg(
    const int* __restrict__ deg, int* __restrict__ rowptr,
    int* __restrict__ cursor, const int* __restrict__ flag)
{
    if (*flag == 0) return;
    __shared__ int sums[SCAN_T];
    const int t = threadIdx.x;
    const int base = t * SCAN_CH;

    int v[SCAN_CH];
    const int4* dp = reinterpret_cast<const int4*>(deg + base);
#pragma unroll
    for (int j = 0; j < SCAN_CH / 4; j++) {
        int4 q = dp[j];
        v[4 * j + 0] = q.x; v[4 * j + 1] = q.y;
        v[4 * j + 2] = q.z; v[4 * j + 3] = q.w;
    }
    int s = 0;
#pragma unroll
    for (int j = 0; j < SCAN_CH; j++) s += v[j];
    sums[t] = s;
    __syncthreads();
    for (int off = 1; off < SCAN_T; off <<= 1) {
        int x = (t >= off) ? sums[t - off] : 0;
        __syncthreads();
        sums[t] += x;
        __syncthreads();
    }
    int run = sums[t] - s;   // exclusive prefix
    if (t == 0) rowptr[0] = 0;
#pragma unroll
    for (int j = 0; j < SCAN_CH; j++) {
        cursor[base + j] = run;
        run += v[j];
        rowptr[base + j + 1] = run;
    }
}

__global__ void scatter_edges(const int* __restrict__ ei, int* __restrict__ cursor,
                              int* __restrict__ csr_src, int E_, int Nn,
                              const int* __restrict__ flag)
{
    if (*flag == 0) return;
    int e = blockIdx.x * blockDim.x + threadIdx.x;
    int tot = E_ + Nn;
    if (e >= tot) return;
    int src, dst;
    if (e < E_) { src = ei[e]; dst = ei[E_ + e]; }
    else        { src = e - E_; dst = src; }
    int pos = atomicAdd(&cursor[dst], 1);
    csr_src[pos] = src;
}

// ---------------------------------------------------------------------------
extern "C" void kernel_launch(void* const* d_in, const int* in_sizes, int n_in,
                              void* d_out, int out_size, void* d_ws, size_t ws_size,
                              hipStream_t stream)
{
    const float* x    = (const float*)d_in[0];
    const int*   ei   = (const int*)d_in[1];
    const int*   flag = (const int*)d_in[2];
    const float* W1 = (const float*)d_in[3];
    const float* as1 = (const float*)d_in[4];
    const float* ad1 = (const float*)d_in[5];
    const float* b1 = (const float*)d_in[6];
    const float* W2 = (const float*)d_in[7];
    const float* as2 = (const float*)d_in[8];
    const float* ad2 = (const float*)d_in[9];
    const float* b2 = (const float*)d_in[10];
    const float* W3 = (const float*)d_in[11];
    const float* as3 = (const float*)d_in[12];
    const float* ad3 = (const float*)d_in[13];
    const float* b3 = (const float*)d_in[14];
    const float* W4 = (const float*)d_in[15];
    const float* as4 = (const float*)d_in[16];
    const float* ad4 = (const float*)d_in[17];
    const float* b4 = (const float*)d_in[18];
    const float* el1w = (const float*)d_in[19];
    const float* el1b = (const float*)d_in[20];
    const float* el2w = (const float*)d_in[21];
    const float* el2b = (const float*)d_in[22];
    const float* dl1w = (const float*)d_in[23];
    const float* dl1b = (const float*)d_in[24];
    const float* dl2w = (const float*)d_in[25];
    const float* dl2b = (const float*)d_in[26];

    const int E_   = in_sizes[1] / 2;
    const int Etot = E_ + NODES;

    char* base = (char*)d_ws;
    size_t off = 0;
    auto carve = [&](size_t bytes) -> void* {
        void* p = base + off;
        off = (off + bytes + 255) & ~(size_t)255;
        return p;
    };
    float* T0  = (float*)carve((size_t)NODES * 128 * 4);
    float* A   = (float*)carve((size_t)NODES * 256 * 4);
    float* T1  = (float*)carve((size_t)NODES * 64 * 4);
    float* Bz  = (float*)carve((size_t)NODES * 32 * 4);
    float* asb = (float*)carve((size_t)NODES * 2 * 4);
    float* adb = (float*)carve((size_t)NODES * 2 * 4);
    float* eb  = (float*)carve((size_t)Etot * 2 * 4);
    float* u1s = (float*)carve(2 * 64 * 4);
    float* u1d = (float*)carve(2 * 64 * 4);
    float* u3s = (float*)carve(2 * 32 * 4);
    float* u3d = (float*)carve(2 * 32 * 4);
    int* deg    = (int*)carve((size_t)SCAN_CAP * 4);
    int* rowptr = (int*)carve((size_t)(SCAN_CAP + 1) * 4);
    int* cursor = (int*)carve((size_t)SCAN_CAP * 4);
    int* csr    = (int*)carve((size_t)Etot * 4);
    (void)ws_size; (void)n_in; (void)out_size;

    float* outp = (float*)d_out;
    float* agg  = T0;

    const int nodeBlocks = (NODES + 3) / 4;
    const int edgeBlocks = (Etot + 255) / 256;
    dim3 blk(256);
    const int rowTiles = (NODES + 63) / 64;

    // ---- CSR build ----
    zero_int<<<(SCAN_CAP + 255) / 256, 256, 0, stream>>>(deg, SCAN_CAP, flag);
    count_deg<<<edgeBlocks, 256, 0, stream>>>(ei, deg, E_, NODES, flag);
    scan_deg<<<1, SCAN_T, 0, stream>>>(deg, rowptr, cursor, flag);
    scatter_edges<<<edgeBlocks, 256, 0, stream>>>(ei, cursor, csr, E_, NODES, flag);

    // ---- Layer 1: GAT(64 -> 128 x 2 heads) + ReLU  [aggregate-then-project] ----
    fold_att<2, 128, 64><<<4, 256, 0, stream>>>(W1, as1, ad1, u1s, u1d, flag);
    att_from_x<64, 2><<<nodeBlocks, blk, 0, stream>>>(x, u1s, u1d, asb, adb, flag);
    gather_e<2><<<edgeBlocks, 256, 0, stream>>>(asb, csr, eb, Etot, flag);
    gat_aggr_x<64, 2><<<nodeBlocks, blk, 0, stream>>>(x, eb, adb, rowptr, csr, agg, flag);
    gemm_xwt<<<dim3(2, rowTiles, 2), blk, 0, stream>>>(agg, 128, W1, b1, A, 256, NODES, 128, 64, 1, flag, 1);

    // ---- Layer 2: GAT(256 -> 32, 1 head) ----
    gemm_xwt<<<dim3(1, rowTiles, 1), blk, 0, stream>>>(A, 256, W2, nullptr, T1, 32, NODES, 32, 256, 0, flag, 1);
    att_from_x<32, 1><<<(NODES + 7) / 8, blk, 0, stream>>>(T1, as2, ad2, asb, adb, flag);
    gather_e<1><<<edgeBlocks, 256, 0, stream>>>(asb, csr, eb, Etot, flag);
    gat_aggr_h<32, 0><<<nodeBlocks, blk, 0, stream>>>(T1, eb, adb, rowptr, csr, b2, Bz, flag);

    // ---- Layer 3: GAT(32 -> 128 x 2 heads) + ReLU  [aggregate-then-project] ----
    fold_att<2, 128, 32><<<4, 256, 0, stream>>>(W3, as3, ad3, u3s, u3d, flag);
    att_from_x<32, 2><<<(NODES + 7) / 8, blk, 0, stream>>>(Bz, u3s, u3d, asb, adb, flag);
    gather_e<2><<<edgeBlocks, 256, 0, stream>>>(asb, csr, eb, Etot, flag);
    gat_aggr_x<32, 2><<<nodeBlocks, blk, 0, stream>>>(Bz, eb, adb, rowptr, csr, agg, flag);
    gemm_xwt<<<dim3(2, rowTiles, 2), blk, 0, stream>>>(agg, 64, W3, b3, A, 256, NODES, 128, 32, 1, flag, 1);

    // ---- Layer 4: GAT(256 -> 64, 1 head) ----
    gemm_xwt<<<dim3(1, rowTiles, 1), blk, 0, stream>>>(A, 256, W4, nullptr, T1, 64, NODES, 64, 256, 0, flag, 1);
    att_from_x<64, 1><<<nodeBlocks, blk, 0, stream>>>(T1, as4, ad4, asb, adb, flag);
    gather_e<1><<<edgeBlocks, 256, 0, stream>>>(asb, csr, eb, Etot, flag);
    gat_aggr_h<64, 0><<<nodeBlocks, blk, 0, stream>>>(T1, eb, adb, rowptr, csr, b4, outp, flag);

    // ---- Dense path (use_neighbors == 0) ----
    gemm_xwt<<<dim3(2, rowTiles, 1), blk, 0, stream>>>(x,  64,  el1w, el1b, T0,   128, NODES, 128, 64, 1, flag, 0);
    gemm_xwt<<<dim3(1, rowTiles, 1), blk, 0, stream>>>(T0, 128, el2w, el2b, Bz,   32,  NODES, 32, 128, 0, flag, 0);
    gemm_xwt<<<dim3(2, rowTiles, 1), blk, 0, stream>>>(Bz, 32,  dl1w, dl1b, A,    128, NODES, 128, 32, 1, flag, 0);
    gemm_xwt<<<dim3(1, rowTiles, 1), blk, 0, stream>>>(A,  128, dl2w, dl2b, outp, 64,  NODES, 64, 128, 0, flag, 0);
}

// Round 7
// 383.260 us; speedup vs baseline: 1.6036x; 1.0469x over previous
//
#include <hip/hip_runtime.h>
#include <hip/hip_bf16.h>
#include <math.h>

#define NODES 30000
#define WAVE 64
#define SCAN_T 1024
#define SCAN_CH 32
#define SCAN_CAP (SCAN_T * SCAN_CH)   // 32768 >= NODES, branchless scan

static __device__ __forceinline__ float lrelu(float x) {
    return (x > 0.f) ? x : 0.2f * x;
}

// ---------------------------------------------------------------------------
// GEMM: out[n, z*M + m] = X[n, z*K + k] @ W[z*M + m, k]^T  (+bias, opt relu)
// If att_s != nullptr (requires gridDim.x == 1, M <= 64): epilogue also emits
// as_out[n] = out_row . att_s,  ad_out[n] = out_row . att_d  (pre-bias).
// ---------------------------------------------------------------------------
__global__ __launch_bounds__(256) void gemm_xwt(
    const float* __restrict__ X, int lda, const float* __restrict__ W,
    const float* __restrict__ bias, float* __restrict__ out, int ldc,
    int Nrows, int M, int K, int relu,
    const float* __restrict__ att_s, const float* __restrict__ att_d,
    float* __restrict__ as_out, float* __restrict__ ad_out,
    const int* __restrict__ flag, int wantFlag)
{
    if (((*flag != 0) ? 1 : 0) != wantFlag) return;

    const int z = blockIdx.z;
    X += (size_t)z * K;
    W += (size_t)z * M * K;
    if (bias) bias += (size_t)z * M;
    out += (size_t)z * M;

    __shared__ float As[16][68];
    __shared__ float Bs[16][68];

    const int t  = threadIdx.x;
    const int tx = t & 15;
    const int ty = t >> 4;
    const int rowBase = blockIdx.y * 64;
    const int colBase = blockIdx.x * 64;

    float acc[4][4];
#pragma unroll
    for (int i = 0; i < 4; i++)
#pragma unroll
        for (int j = 0; j < 4; j++) acc[i][j] = 0.f;

    const int r_ld = t >> 2;
    const int k_ld = (t & 3) * 4;

    for (int kt = 0; kt < K; kt += 16) {
        float4 av = make_float4(0.f, 0.f, 0.f, 0.f);
        int grow = rowBase + r_ld;
        if (grow < Nrows)
            av = *reinterpret_cast<const float4*>(&X[(size_t)grow * lda + kt + k_ld]);
        As[k_ld + 0][r_ld] = av.x;
        As[k_ld + 1][r_ld] = av.y;
        As[k_ld + 2][r_ld] = av.z;
        As[k_ld + 3][r_ld] = av.w;
        float4 bv = make_float4(0.f, 0.f, 0.f, 0.f);
        int gm = colBase + r_ld;
        if (gm < M)
            bv = *reinterpret_cast<const float4*>(&W[(size_t)gm * K + kt + k_ld]);
        Bs[k_ld + 0][r_ld] = bv.x;
        Bs[k_ld + 1][r_ld] = bv.y;
        Bs[k_ld + 2][r_ld] = bv.z;
        Bs[k_ld + 3][r_ld] = bv.w;
        __syncthreads();

#pragma unroll
        for (int kk = 0; kk < 16; ++kk) {
            const float4 a = *reinterpret_cast<const float4*>(&As[kk][ty * 4]);
            const float4 b = *reinterpret_cast<const float4*>(&Bs[kk][tx * 4]);
            acc[0][0] += a.x * b.x; acc[0][1] += a.x * b.y; acc[0][2] += a.x * b.z; acc[0][3] += a.x * b.w;
            acc[1][0] += a.y * b.x; acc[1][1] += a.y * b.y; acc[1][2] += a.y * b.z; acc[1][3] += a.y * b.w;
            acc[2][0] += a.z * b.x; acc[2][1] += a.z * b.y; acc[2][2] += a.z * b.z; acc[2][3] += a.z * b.w;
            acc[3][0] += a.w * b.x; acc[3][1] += a.w * b.y; acc[3][2] += a.w * b.z; acc[3][3] += a.w * b.w;
        }
        __syncthreads();
    }

    const int col0 = colBase + tx * 4;
#pragma unroll
    for (int i = 0; i < 4; i++) {
        int row = rowBase + ty * 4 + i;
        if (row >= Nrows) continue;
        if (col0 >= M) continue;
        float4 v = make_float4(acc[i][0], acc[i][1], acc[i][2], acc[i][3]);
        if (bias) {
            v.x += bias[col0 + 0]; v.y += bias[col0 + 1];
            v.z += bias[col0 + 2]; v.w += bias[col0 + 3];
        }
        if (relu) {
            v.x = fmaxf(v.x, 0.f); v.y = fmaxf(v.y, 0.f);
            v.z = fmaxf(v.z, 0.f); v.w = fmaxf(v.w, 0.f);
        }
        *reinterpret_cast<float4*>(&out[(size_t)row * ldc + col0]) = v;
    }

    // fused attention dots (M <= 64, single column tile, bias/relu off)
    if (att_s) {
        float4 asv = make_float4(0.f, 0.f, 0.f, 0.f), adv = asv;
        if (col0 < M) {
            asv = *reinterpret_cast<const float4*>(&att_s[col0]);
            adv = *reinterpret_cast<const float4*>(&att_d[col0]);
        }
#pragma unroll
        for (int i = 0; i < 4; i++) {
            float ps = acc[i][0] * asv.x + acc[i][1] * asv.y + acc[i][2] * asv.z + acc[i][3] * asv.w;
            float pd = acc[i][0] * adv.x + acc[i][1] * adv.y + acc[i][2] * adv.z + acc[i][3] * adv.w;
#pragma unroll
            for (int off = 8; off; off >>= 1) {
                ps += __shfl_xor(ps, off);
                pd += __shfl_xor(pd, off);
            }
            int row = rowBase + ty * 4 + i;
            if (tx == 0 && row < Nrows) {
                as_out[row] = ps;
                ad_out[row] = pd;
            }
        }
    }
}

// ---------------------------------------------------------------------------
// Fold attention vectors into input space: u[h,k] = sum_f att[h,f] * W[h*F+f, k]
// ---------------------------------------------------------------------------
template <int HH, int F, int K>
__global__ __launch_bounds__(256) void fold_att(
    const float* __restrict__ W, const float* __restrict__ as_,
    const float* __restrict__ ad_, float* __restrict__ us,
    float* __restrict__ ud, const int* __restrict__ flag)
{
    if (*flag == 0) return;
    const int b   = blockIdx.x;        // 0 .. 2*HH-1
    const int sel = b / HH;
    const int h   = b % HH;
    const float* att = sel ? ad_ : as_;
    float* uo = sel ? ud : us;

    constexpr int NG = 256 / K;
    const int k  = threadIdx.x % K;
    const int fg = threadIdx.x / K;

    float s = 0.f;
#pragma unroll
    for (int f = fg; f < F; f += NG)
        s += att[h * F + f] * W[(size_t)(h * F + f) * K + k];

    __shared__ float red[256];
    red[threadIdx.x] = s;
    __syncthreads();
    if (fg == 0) {
        float tot = s;
#pragma unroll
        for (int g = 1; g < NG; g++) tot += red[g * K + k];
        uo[h * K + k] = tot;
    }
}

// ---------------------------------------------------------------------------
// a_s[n,h] = feat[n,:] . u_s[h,:]  (and a_d).  64/K nodes per wave.
// ---------------------------------------------------------------------------
template <int K, int HH>
__global__ __launch_bounds__(256) void att_from_x(
    const float* __restrict__ xin, const float* __restrict__ us,
    const float* __restrict__ ud, float* __restrict__ as_out,
    float* __restrict__ ad_out, const int* __restrict__ flag)
{
    if (*flag == 0) return;
    constexpr int NPW = WAVE / K;
    const int wid  = threadIdx.x >> 6;
    const int lane = threadIdx.x & 63;
    const int sub  = lane / K;
    const int col  = lane % K;
    const int node = (blockIdx.x * 4 + wid) * NPW + sub;

    float v = 0.f;
    if (node < NODES) v = xin[(size_t)node * K + col];
    float ps[HH], pd[HH];
#pragma unroll
    for (int h = 0; h < HH; h++) {
        ps[h] = v * us[h * K + col];
        pd[h] = v * ud[h * K + col];
    }
#pragma unroll
    for (int off = K / 2; off; off >>= 1) {
#pragma unroll
        for (int h = 0; h < HH; h++) {
            ps[h] += __shfl_xor(ps[h], off);
            pd[h] += __shfl_xor(pd[h], off);
        }
    }
    if (col == 0 && node < NODES) {
#pragma unroll
        for (int h = 0; h < HH; h++) {
            as_out[node * HH + h] = ps[h];
            ad_out[node * HH + h] = pd[h];
        }
    }
}

// ---------------------------------------------------------------------------
// Fused GAT aggregation of RAW features (layers 1/3, aggregate-then-project).
// Fast path (deg <= 64): one edge per lane, softmax entirely in registers.
// Gather loop is WAVE-UNIFORM trip count so every __shfl executes with all
// 64 lanes active (ds_bpermute from an inactive lane loses the data).
// ---------------------------------------------------------------------------
template <int K, int HH>
__global__ __launch_bounds__(256) void gat_aggr_x(
    const float* __restrict__ xin, const float* __restrict__ as_,
    const float* __restrict__ ad_, const int* __restrict__ rowptr,
    const int* __restrict__ csr_src, float* __restrict__ agg,
    const int* __restrict__ flag)
{
    if (*flag == 0) return;
    const int node = blockIdx.x * 4 + (threadIdx.x >> 6);
    const int lane = threadIdx.x & 63;
    if (node >= NODES) return;

    const int beg = rowptr[node], end = rowptr[node + 1];
    const int deg = end - beg;

    float adv[HH];
#pragma unroll
    for (int h = 0; h < HH; h++) adv[h] = ad_[node * HH + h];

    float wl[HH];     // fast path: this lane's edge weight numerator
    float mx[HH], rden[HH];
    const bool fast = (deg <= WAVE);

    if (fast) {
        float e[HH];
        int i = beg + lane;
        if (i < end) {
            int s = csr_src[i];
#pragma unroll
            for (int h = 0; h < HH; h++)
                e[h] = lrelu(as_[s * HH + h] + adv[h]);
        } else {
#pragma unroll
            for (int h = 0; h < HH; h++) e[h] = -1e30f;
        }
#pragma unroll
        for (int h = 0; h < HH; h++) {
            mx[h] = e[h];
#pragma unroll
            for (int off = 32; off; off >>= 1)
                mx[h] = fmaxf(mx[h], __shfl_xor(mx[h], off));
            float ex = __expf(e[h] - mx[h]);
            wl[h] = ex;
            float dn = ex;
#pragma unroll
            for (int off = 32; off; off >>= 1)
                dn += __shfl_xor(dn, off);
            rden[h] = 1.f / dn;
        }
    } else {
        float den[HH];
#pragma unroll
        for (int h = 0; h < HH; h++) { mx[h] = -1e30f; den[h] = 0.f; }
        for (int i = beg + lane; i < end; i += WAVE) {
            int s = csr_src[i];
#pragma unroll
            for (int h = 0; h < HH; h++)
                mx[h] = fmaxf(mx[h], lrelu(as_[s * HH + h] + adv[h]));
        }
#pragma unroll
        for (int h = 0; h < HH; h++)
#pragma unroll
            for (int off = 32; off; off >>= 1)
                mx[h] = fmaxf(mx[h], __shfl_xor(mx[h], off));
        for (int i = beg + lane; i < end; i += WAVE) {
            int s = csr_src[i];
#pragma unroll
            for (int h = 0; h < HH; h++)
                den[h] += __expf(lrelu(as_[s * HH + h] + adv[h]) - mx[h]);
        }
#pragma unroll
        for (int h = 0; h < HH; h++) {
#pragma unroll
            for (int off = 32; off; off >>= 1)
                den[h] += __shfl_xor(den[h], off);
            rden[h] = 1.f / den[h];
        }
    }

    constexpr int LPG = K / 4;
    constexpr int GR  = WAVE / LPG;
    const int esub = lane / LPG;
    const int c4   = lane % LPG;

    float4 acc[HH];
#pragma unroll
    for (int h = 0; h < HH; h++) acc[h] = make_float4(0.f, 0.f, 0.f, 0.f);

    if (fast) {
        const int iters = (deg + GR - 1) / GR;   // wave-uniform
        for (int it = 0; it < iters; ++it) {
            const int i = beg + it * GR + esub;
            const bool valid = (i < end);
            const int srcl = valid ? (i - beg) : 0;
            float w[HH];
#pragma unroll
            for (int h = 0; h < HH; h++)
                w[h] = __shfl(wl[h], srcl);      // all lanes active here
            if (valid) {
                int s = csr_src[i];
                float4 xv = *reinterpret_cast<const float4*>(&xin[(size_t)s * K + c4 * 4]);
#pragma unroll
                for (int h = 0; h < HH; h++) {
                    acc[h].x += xv.x * w[h];
                    acc[h].y += xv.y * w[h];
                    acc[h].z += xv.z * w[h];
                    acc[h].w += xv.w * w[h];
                }
            }
        }
    } else {
        for (int i = beg + esub; i < end; i += GR) {
            int s = csr_src[i];
            float w[HH];
#pragma unroll
            for (int h = 0; h < HH; h++)
                w[h] = __expf(lrelu(as_[s * HH + h] + adv[h]) - mx[h]);
            float4 xv = *reinterpret_cast<const float4*>(&xin[(size_t)s * K + c4 * 4]);
#pragma unroll
            for (int h = 0; h < HH; h++) {
                acc[h].x += xv.x * w[h];
                acc[h].y += xv.y * w[h];
                acc[h].z += xv.z * w[h];
                acc[h].w += xv.w * w[h];
            }
        }
    }
#pragma unroll
    for (int off = LPG; off < WAVE; off <<= 1) {
#pragma unroll
        for (int h = 0; h < HH; h++) {
            acc[h].x += __shfl_xor(acc[h].x, off);
            acc[h].y += __shfl_xor(acc[h].y, off);
            acc[h].z += __shfl_xor(acc[h].z, off);
            acc[h].w += __shfl_xor(acc[h].w, off);
        }
    }
    if (esub == 0) {
#pragma unroll
        for (int h = 0; h < HH; h++) {
            float4 o = make_float4(acc[h].x * rden[h], acc[h].y * rden[h],
                                   acc[h].z * rden[h], acc[h].w * rden[h]);
            *reinterpret_cast<float4*>(&agg[(size_t)node * (HH * K) + h * K + c4 * 4]) = o;
        }
    }
}

// ---------------------------------------------------------------------------
// Fused GAT aggregation of PROJECTED features (layers 2/4), +bias (+relu).
// Same fast/slow structure, single head, wave-uniform gather loop.
// ---------------------------------------------------------------------------
template <int HF, int RELU>
__global__ __launch_bounds__(256) void gat_aggr_h(
    const float* __restrict__ hsrc, const float* __restrict__ as_,
    const float* __restrict__ ad_, const int* __restrict__ rowptr,
    const int* __restrict__ csr_src, const float* __restrict__ bias,
    float* __restrict__ out, const int* __restrict__ flag)
{
    if (*flag == 0) return;
    const int node = blockIdx.x * 4 + (threadIdx.x >> 6);
    const int lane = threadIdx.x & 63;
    if (node >= NODES) return;

    const int beg = rowptr[node], end = rowptr[node + 1];
    const int deg = end - beg;
    const float adv = ad_[node];

    float wl, mx, rden;
    const bool fast = (deg <= WAVE);

    if (fast) {
        int i = beg + lane;
        float e = -1e30f;
        if (i < end) {
            int s = csr_src[i];
            e = lrelu(as_[s] + adv);
        }
        mx = e;
#pragma unroll
        for (int off = 32; off; off >>= 1)
            mx = fmaxf(mx, __shfl_xor(mx, off));
        wl = __expf(e - mx);
        float dn = wl;
#pragma unroll
        for (int off = 32; off; off >>= 1)
            dn += __shfl_xor(dn, off);
        rden = 1.f / dn;
    } else {
        mx = -1e30f;
        float den = 0.f;
        for (int i = beg + lane; i < end; i += WAVE) {
            int s = csr_src[i];
            mx = fmaxf(mx, lrelu(as_[s] + adv));
        }
#pragma unroll
        for (int off = 32; off; off >>= 1)
            mx = fmaxf(mx, __shfl_xor(mx, off));
        for (int i = beg + lane; i < end; i += WAVE) {
            int s = csr_src[i];
            den += __expf(lrelu(as_[s] + adv) - mx);
        }
#pragma unroll
        for (int off = 32; off; off >>= 1)
            den += __shfl_xor(den, off);
        rden = 1.f / den;
        wl = 0.f;
    }

    constexpr int LPG = HF / 4;
    constexpr int GR  = WAVE / LPG;
    const int esub = lane / LPG;
    const int c4   = lane % LPG;

    float4 acc = make_float4(0.f, 0.f, 0.f, 0.f);
    if (fast) {
        const int iters = (deg + GR - 1) / GR;   // wave-uniform
        for (int it = 0; it < iters; ++it) {
            const int i = beg + it * GR + esub;
            const bool valid = (i < end);
            const int srcl = valid ? (i - beg) : 0;
            float w = __shfl(wl, srcl);          // all lanes active here
            if (valid) {
                int s = csr_src[i];
                float4 hv = *reinterpret_cast<const float4*>(&hsrc[(size_t)s * HF + c4 * 4]);
                acc.x += hv.x * w; acc.y += hv.y * w; acc.z += hv.z * w; acc.w += hv.w * w;
            }
        }
    } else {
        for (int i = beg + esub; i < end; i += GR) {
            int s = csr_src[i];
            float w = __expf(lrelu(as_[s] + adv) - mx);
            float4 hv = *reinterpret_cast<const float4*>(&hsrc[(size_t)s * HF + c4 * 4]);
            acc.x += hv.x * w; acc.y += hv.y * w; acc.z += hv.z * w; acc.w += hv.w * w;
        }
    }
#pragma unroll
    for (int off = LPG; off < WAVE; off <<= 1) {
        acc.x += __shfl_xor(acc.x, off);
        acc.y += __shfl_xor(acc.y, off);
        acc.z += __shfl_xor(acc.z, off);
        acc.w += __shfl_xor(acc.w, off);
    }
    if (esub == 0) {
        float4 bv = *reinterpret_cast<const float4*>(&bias[c4 * 4]);
        float4 o = make_float4(acc.x * rden + bv.x, acc.y * rden + bv.y,
                               acc.z * rden + bv.z, acc.w * rden + bv.w);
        if (RELU) {
            o.x = fmaxf(o.x, 0.f); o.y = fmaxf(o.y, 0.f);
            o.z = fmaxf(o.z, 0.f); o.w = fmaxf(o.w, 0.f);
        }
        *reinterpret_cast<float4*>(&out[(size_t)node * HF + c4 * 4]) = o;
    }
}

// ---------------------------------------------------------------------------
// CSR build kernels
// ---------------------------------------------------------------------------
__global__ void zero_int(int* __restrict__ p, int n, const int* __restrict__ flag)
{
    if (*flag == 0) return;
    for (int i = blockIdx.x * blockDim.x + threadIdx.x; i < n; i += gridDim.x * blockDim.x)
        p[i] = 0;
}

__global__ void count_deg(const int* __restrict__ ei, int* __restrict__ deg,
                          int E_, int Nn, const int* __restrict__ flag)
{
    if (*flag == 0) return;
    int e = blockIdx.x * blockDim.x + threadIdx.x;
    int tot = E_ + Nn;
    if (e >= tot) return;
    int dst = (e < E_) ? ei[E_ + e] : (e - E_);
    atomicAdd(&deg[dst], 1);
}

// Branchless single-block scan over SCAN_CAP (deg zero-padded).
// Writes rowptr[0..SCAN_CAP] AND cursor[i] = rowptr[i].
__global__ __launch_bounds__(SCAN_T) void scan_deg(
    const int* __restrict__ deg, int* __restrict__ rowptr,
    int* __restrict__ cursor, const int* __restrict__ flag)
{
    if (*flag == 0) return;
    __shared__ int sums[SCAN_T];
    const int t = threadIdx.x;
    const int base = t * SCAN_CH;

    int v[SCAN_CH];
    const int4* dp = reinterpret_cast<const int4*>(deg + base);
#pragma unroll
    for (int j = 0; j < SCAN_CH / 4; j++) {
        int4 q = dp[j];
        v[4 * j + 0] = q.x; v[4 * j + 1] = q.y;
        v[4 * j + 2] = q.z; v[4 * j + 3] = q.w;
    }
    int s = 0;
#pragma unroll
    for (int j = 0; j < SCAN_CH; j++) s += v[j];
    sums[t] = s;
    __syncthreads();
    for (int off = 1; off < SCAN_T; off <<= 1) {
        int x = (t >= off) ? sums[t - off] : 0;
        __syncthreads();
        sums[t] += x;
        __syncthreads();
    }
    int run = sums[t] - s;
    if (t == 0) rowptr[0] = 0;
#pragma unroll
    for (int j = 0; j < SCAN_CH; j++) {
        cursor[base + j] = run;
        run += v[j];
        rowptr[base + j + 1] = run;
    }
}

__global__ void scatter_edges(const int* __restrict__ ei, int* __restrict__ cursor,
                              int* __restrict__ csr_src, int E_, int Nn,
                              const int* __restrict__ flag)
{
    if (*flag == 0) return;
    int e = blockIdx.x * blockDim.x + threadIdx.x;
    int tot = E_ + Nn;
    if (e >= tot) return;
    int src, dst;
    if (e < E_) { src = ei[e]; dst = ei[E_ + e]; }
    else        { src = e - E_; dst = src; }
    int pos = atomicAdd(&cursor[dst], 1);
    csr_src[pos] = src;
}

// ---------------------------------------------------------------------------
extern "C" void kernel_launch(void* const* d_in, const int* in_sizes, int n_in,
                              void* d_out, int out_size, void* d_ws, size_t ws_size,
                              hipStream_t stream)
{
    const float* x    = (const float*)d_in[0];
    const int*   ei   = (const int*)d_in[1];
    const int*   flag = (const int*)d_in[2];
    const float* W1 = (const float*)d_in[3];
    const float* as1 = (const float*)d_in[4];
    const float* ad1 = (const float*)d_in[5];
    const float* b1 = (const float*)d_in[6];
    const float* W2 = (const float*)d_in[7];
    const float* as2 = (const float*)d_in[8];
    const float* ad2 = (const float*)d_in[9];
    const float* b2 = (const float*)d_in[10];
    const float* W3 = (const float*)d_in[11];
    const float* as3 = (const float*)d_in[12];
    const float* ad3 = (const float*)d_in[13];
    const float* b3 = (const float*)d_in[14];
    const float* W4 = (const float*)d_in[15];
    const float* as4 = (const float*)d_in[16];
    const float* ad4 = (const float*)d_in[17];
    const float* b4 = (const float*)d_in[18];
    const float* el1w = (const float*)d_in[19];
    const float* el1b = (const float*)d_in[20];
    const float* el2w = (const float*)d_in[21];
    const float* el2b = (const float*)d_in[22];
    const float* dl1w = (const float*)d_in[23];
    const float* dl1b = (const float*)d_in[24];
    const float* dl2w = (const float*)d_in[25];
    const float* dl2b = (const float*)d_in[26];

    const int E_   = in_sizes[1] / 2;
    const int Etot = E_ + NODES;

    char* base = (char*)d_ws;
    size_t off = 0;
    auto carve = [&](size_t bytes) -> void* {
        void* p = base + off;
        off = (off + bytes + 255) & ~(size_t)255;
        return p;
    };
    float* T0  = (float*)carve((size_t)NODES * 128 * 4);
    float* A   = (float*)carve((size_t)NODES * 256 * 4);
    float* T1  = (float*)carve((size_t)NODES * 64 * 4);
    float* Bz  = (float*)carve((size_t)NODES * 32 * 4);
    float* asb = (float*)carve((size_t)NODES * 2 * 4);
    float* adb = (float*)carve((size_t)NODES * 2 * 4);
    float* u1s = (float*)carve(2 * 64 * 4);
    float* u1d = (float*)carve(2 * 64 * 4);
    float* u3s = (float*)carve(2 * 32 * 4);
    float* u3d = (float*)carve(2 * 32 * 4);
    int* deg    = (int*)carve((size_t)SCAN_CAP * 4);
    int* rowptr = (int*)carve((size_t)(SCAN_CAP + 1) * 4);
    int* cursor = (int*)carve((size_t)SCAN_CAP * 4);
    int* csr    = (int*)carve((size_t)Etot * 4);
    (void)ws_size; (void)n_in; (void)out_size;

    float* outp = (float*)d_out;
    float* agg  = T0;

    const int nodeBlocks = (NODES + 3) / 4;
    const int edgeBlocks = (Etot + 255) / 256;
    dim3 blk(256);
    const int rowTiles = (NODES + 63) / 64;

    // ---- CSR build ----
    zero_int<<<(SCAN_CAP + 255) / 256, 256, 0, stream>>>(deg, SCAN_CAP, flag);
    count_deg<<<edgeBlocks, 256, 0, stream>>>(ei, deg, E_, NODES, flag);
    scan_deg<<<1, SCAN_T, 0, stream>>>(deg, rowptr, cursor, flag);
    scatter_edges<<<edgeBlocks, 256, 0, stream>>>(ei, cursor, csr, E_, NODES, flag);

    // ---- Layer 1: GAT(64 -> 128 x 2 heads) + ReLU  [aggregate-then-project] ----
    fold_att<2, 128, 64><<<4, 256, 0, stream>>>(W1, as1, ad1, u1s, u1d, flag);
    att_from_x<64, 2><<<nodeBlocks, blk, 0, stream>>>(x, u1s, u1d, asb, adb, flag);
    gat_aggr_x<64, 2><<<nodeBlocks, blk, 0, stream>>>(x, asb, adb, rowptr, csr, agg, flag);
    gemm_xwt<<<dim3(2, rowTiles, 2), blk, 0, stream>>>(agg, 128, W1, b1, A, 256, NODES, 128, 64, 1,
                                                       nullptr, nullptr, nullptr, nullptr, flag, 1);

    // ---- Layer 2: GAT(256 -> 32, 1 head): gemm emits h AND att dots ----
    gemm_xwt<<<dim3(1, rowTiles, 1), blk, 0, stream>>>(A, 256, W2, nullptr, T1, 32, NODES, 32, 256, 0,
                                                       as2, ad2, asb, adb, flag, 1);
    gat_aggr_h<32, 0><<<nodeBlocks, blk, 0, stream>>>(T1, asb, adb, rowptr, csr, b2, Bz, flag);

    // ---- Layer 3: GAT(32 -> 128 x 2 heads) + ReLU  [aggregate-then-project] ----
    fold_att<2, 128, 32><<<4, 256, 0, stream>>>(W3, as3, ad3, u3s, u3d, flag);
    att_from_x<32, 2><<<(NODES + 7) / 8, blk, 0, stream>>>(Bz, u3s, u3d, asb, adb, flag);
    gat_aggr_x<32, 2><<<nodeBlocks, blk, 0, stream>>>(Bz, asb, adb, rowptr, csr, agg, flag);
    gemm_xwt<<<dim3(2, rowTiles, 2), blk, 0, stream>>>(agg, 64, W3, b3, A, 256, NODES, 128, 32, 1,
                                                       nullptr, nullptr, nullptr, nullptr, flag, 1);

    // ---- Layer 4: GAT(256 -> 64, 1 head): gemm emits h AND att dots ----
    gemm_xwt<<<dim3(1, rowTiles, 1), blk, 0, stream>>>(A, 256, W4, nullptr, T1, 64, NODES, 64, 256, 0,
                                                       as4, ad4, asb, adb, flag, 1);
    gat_aggr_h<64, 0><<<nodeBlocks, blk, 0, stream>>>(T1, asb, adb, rowptr, csr, b4, outp, flag);

    // ---- Dense path (use_neighbors == 0) ----
    gemm_xwt<<<dim3(2, rowTiles, 1), blk, 0, stream>>>(x,  64,  el1w, el1b, T0,   128, NODES, 128, 64, 1,
                                                       nullptr, nullptr, nullptr, nullptr, flag, 0);
    gemm_xwt<<<dim3(1, rowTiles, 1), blk, 0, stream>>>(T0, 128, el2w, el2b, Bz,   32,  NODES, 32, 128, 0,
                                                       nullptr, nullptr, nullptr, nullptr, flag, 0);
    gemm_xwt<<<dim3(2, rowTiles, 1), blk, 0, stream>>>(Bz, 32,  dl1w, dl1b, A,    128, NODES, 128, 32, 1,
                                                       nullptr, nullptr, nullptr, nullptr, flag, 0);
    gemm_xwt<<<dim3(1, rowTiles, 1), blk, 0, stream>>>(A,  128, dl2w, dl2b, outp, 64,  NODES, 64, 128, 0,
                                                       nullptr, nullptr, nullptr, nullptr, flag, 0);
}